// Round 7
// baseline (415.743 us; speedup 1.0000x reference)
//
#include <hip/hip_runtime.h>
#include <hip/hip_bf16.h>
#include <math.h>

#define T_LEN 20000
#define HID 150
#define TS 20000   // transposed U/V/P row stride (shorts)

typedef __attribute__((ext_vector_type(8))) __bf16 bf16x8;
typedef __attribute__((ext_vector_type(4))) float f32x4;

__device__ __forceinline__ short f2bf(float f) {
    unsigned u = __float_as_uint(f);
    u = (u + 0x7fff + ((u >> 16) & 1)) >> 16;
    return (short)u;
}

__device__ __forceinline__ unsigned pk2(float a, float b) {
    __hip_bfloat162 h = __float22bfloat162_rn(make_float2(a, b));
    return *(unsigned*)&h;
}

__device__ __forceinline__ bf16x8 cvt8(float4 a, float4 b) {
    union { unsigned u[4]; bf16x8 v; } r;
    r.u[0] = pk2(a.x, a.y);
    r.u[1] = pk2(a.z, a.w);
    r.u[2] = pk2(b.x, b.y);
    r.u[3] = pk2(b.z, b.w);
    return r.v;
}

__device__ __forceinline__ bf16x8 pack8(const float* v) {
    union { unsigned u[4]; bf16x8 b; } r;
    r.u[0] = pk2(v[0], v[1]); r.u[1] = pk2(v[2], v[3]);
    r.u[2] = pk2(v[4], v[5]); r.u[3] = pk2(v[6], v[7]);
    return r.b;
}

// ---------------------------------------------------------------------------
// wprep: bf16 transposed weights (unchanged layout, shorts):
//   [0,66560)        Bt0 [160][416]  sc_W1 rows   0..399  (U)
//   [66560,133120)   Bt1 [160][416]  sc_W1 rows 400..799  (V)
//   [133120,199680)  At1 [160][416]  attn_W1
//   [199680,266240)  Bt2 [160][416]  sc_W1 rows 800..1099 (P, K=300)
//   [266240,291840)  At2 [160][160]  attn_W2
//   [291840,318720)  W2t [160][168]  sc_W2
// ---------------------------------------------------------------------------
__global__ __launch_bounds__(256) void wprep(
    const float* __restrict__ sc_W1, const float* __restrict__ attn_W1,
    const float* __restrict__ attn_W2, const float* __restrict__ sc_W2,
    short* __restrict__ wbf)
{
    int t = blockIdx.x * 256 + threadIdx.x;
    if (t >= 318720) return;
    float v = 0.f;
    if (t < 133120) {
        int y = t / 66560, r = t - y * 66560;
        int nn = r / 416, k = r - nn * 416;
        if (nn < HID && k < 400) v = sc_W1[(long)(y * 400 + k) * HID + nn];
    } else if (t < 199680) {
        int r = t - 133120;
        int nn = r / 416, k = r - nn * 416;
        if (nn < HID && k < 400) v = attn_W1[(long)k * HID + nn];
    } else if (t < 266240) {
        int r = t - 199680;
        int nn = r / 416, k = r - nn * 416;
        if (nn < HID && k < 300) v = sc_W1[(long)(800 + k) * HID + nn];
    } else if (t < 291840) {
        int r = t - 266240;
        int nn = r / 160, k = r - nn * 160;
        if (nn < HID && k < HID) v = attn_W2[(long)k * HID + nn];
    } else {
        int r = t - 291840;
        int nn = r / 168, k = r - nn * 168;
        if (nn < HID && k < HID) v = sc_W2[(long)k * HID + nn];
    }
    wbf[t] = f2bf(v);
}

// ---------------------------------------------------------------------------
// fusedA: 16 rows/block, grid 1250. One states pass -> UT, VT (bf16 TRANSPOSED
// [160][20000], sc_b1 folded into UT, cols>=150 zero) + attn logits.
// 30 n-tiles split 8/8/7/7 across waves; attn tail 3/3/2/2 + LDS reduce.
// ---------------------------------------------------------------------------
__global__ __launch_bounds__(256) void fusedA(
    const float* __restrict__ states, const short* __restrict__ wbf,
    const float* __restrict__ scb1, const float* __restrict__ ab1,
    const float* __restrict__ ab2, const float* __restrict__ aW3,
    const float* __restrict__ ab3,
    short* __restrict__ UT, short* __restrict__ VT, float* __restrict__ logits)
{
    __shared__ short h1s[16 * 168];
    __shared__ float red[16][4];
    const int tid = threadIdx.x;
    const int w = tid >> 6, lane = tid & 63;
    const int ml = lane & 15, kg = lane >> 4;
    const int m0 = blockIdx.x * 16;          // 1250 * 16 = 20000 exact

    const float* Arow = states + (long)(m0 + ml) * 400;
    const int nT = (w < 2) ? 8 : 7;

    f32x4 acc[8];
    #pragma unroll
    for (int t = 0; t < 8; ++t) acc[t] = (f32x4){0.f, 0.f, 0.f, 0.f};

    for (int ks = 0; ks < 13; ++ks) {
        int k = ks * 32 + kg * 8;
        float4 a0 = make_float4(0.f, 0.f, 0.f, 0.f);
        float4 a1 = make_float4(0.f, 0.f, 0.f, 0.f);
        if (k + 4 <= 400) a0 = *(const float4*)&Arow[k];
        if (k + 8 <= 400) a1 = *(const float4*)&Arow[k + 4];
        bf16x8 af = cvt8(a0, a1);
        #pragma unroll
        for (int t = 0; t < 8; ++t) {
            if (t < nT) {
                int nt = 4 * t + w;
                bf16x8 bf = *(const bf16x8*)&wbf[(long)(nt * 16 + ml) * 416 + k];
                acc[t] = __builtin_amdgcn_mfma_f32_16x16x32_bf16(af, bf, acc[t], 0, 0, 0);
            }
        }
    }

    #pragma unroll
    for (int t = 0; t < 8; ++t) {
        if (t < nT) {
            int nt = 4 * t + w;
            if (nt < 10) {                    // UT (+sc_b1)
                int col = nt * 16 + ml;
                float bv = (col < HID) ? scb1[col] : 0.f;
                float v0 = 0.f, v1 = 0.f, v2 = 0.f, v3 = 0.f;
                if (col < HID) {
                    v0 = acc[t][0] + bv; v1 = acc[t][1] + bv;
                    v2 = acc[t][2] + bv; v3 = acc[t][3] + bv;
                }
                *(uint2*)&UT[(long)col * TS + m0 + kg * 4] =
                    make_uint2(pk2(v0, v1), pk2(v2, v3));
            } else if (nt < 20) {             // VT
                int col = (nt - 10) * 16 + ml;
                float v0 = 0.f, v1 = 0.f, v2 = 0.f, v3 = 0.f;
                if (col < HID) {
                    v0 = acc[t][0]; v1 = acc[t][1];
                    v2 = acc[t][2]; v3 = acc[t][3];
                }
                *(uint2*)&VT[(long)col * TS + m0 + kg * 4] =
                    make_uint2(pk2(v0, v1), pk2(v2, v3));
            } else {                          // X1 -> relu -> bf16 LDS
                int col = (nt - 20) * 16 + ml;
                float bv = (col < HID) ? ab1[col] : 0.f;
                #pragma unroll
                for (int r = 0; r < 4; ++r) {
                    int row = kg * 4 + r;
                    float v = (col < HID) ? fmaxf(acc[t][r] + bv, 0.f) : 0.f;
                    h1s[row * 168 + col] = f2bf(v);
                }
            }
        }
    }
    __syncthreads();

    // attn layer 2 (K=160) tiles split 3/3/2/2 + relu-dot-W3 epilogue
    const short* At2 = wbf + 266240;
    bf16x8 af2[5];
    #pragma unroll
    for (int ks = 0; ks < 5; ++ks)
        af2[ks] = *(const bf16x8*)&h1s[ml * 168 + ks * 32 + kg * 8];

    const int nT2 = (w < 2) ? 3 : 2;
    float score[4] = {0.f, 0.f, 0.f, 0.f};
    #pragma unroll
    for (int t = 0; t < 3; ++t) {
        if (t < nT2) {
            int nt = 4 * t + w;
            f32x4 a2 = {0.f, 0.f, 0.f, 0.f};
            #pragma unroll
            for (int ks = 0; ks < 5; ++ks) {
                bf16x8 bf = *(const bf16x8*)&At2[(long)(nt * 16 + ml) * 160 + ks * 32 + kg * 8];
                a2 = __builtin_amdgcn_mfma_f32_16x16x32_bf16(af2[ks], bf, a2, 0, 0, 0);
            }
            int col = nt * 16 + ml;
            float b2v = (col < HID) ? ab2[col] : 0.f;
            float w3v = (col < HID) ? aW3[col] : 0.f;
            #pragma unroll
            for (int r = 0; r < 4; ++r)
                score[r] += fmaxf(a2[r] + b2v, 0.f) * w3v;
        }
    }
    #pragma unroll
    for (int r = 0; r < 4; ++r) {
        score[r] += __shfl_xor(score[r], 1);
        score[r] += __shfl_xor(score[r], 2);
        score[r] += __shfl_xor(score[r], 4);
        score[r] += __shfl_xor(score[r], 8);
    }
    if (ml == 0) {
        #pragma unroll
        for (int r = 0; r < 4; ++r) red[kg * 4 + r][w] = score[r];
    }
    __syncthreads();
    if (tid < 16)
        logits[m0 + tid] = red[tid][0] + red[tid][1] + red[tid][2] + red[tid][3] + ab3[0];
}

// ---------------------------------------------------------------------------
// pkern: PT = (embeds @ sc_W1[800:1100])^T bf16 [160][20000]. 16 rows/block.
// ---------------------------------------------------------------------------
__global__ __launch_bounds__(256) void pkern(
    const float* __restrict__ embeds, const short* __restrict__ wbf,
    short* __restrict__ PT)
{
    const int tid = threadIdx.x;
    const int w = tid >> 6, lane = tid & 63;
    const int ml = lane & 15, kg = lane >> 4;
    const int m0 = blockIdx.x * 16;
    const short* Bt = wbf + 199680;

    const float* Arow = embeds + (long)(m0 + ml) * 300;
    const int nT = (w < 2) ? 3 : 2;

    f32x4 acc[3];
    #pragma unroll
    for (int t = 0; t < 3; ++t) acc[t] = (f32x4){0.f, 0.f, 0.f, 0.f};

    for (int ks = 0; ks < 10; ++ks) {
        int k = ks * 32 + kg * 8;
        float4 a0 = make_float4(0.f, 0.f, 0.f, 0.f);
        float4 a1 = make_float4(0.f, 0.f, 0.f, 0.f);
        if (k + 4 <= 300) a0 = *(const float4*)&Arow[k];
        if (k + 8 <= 300) a1 = *(const float4*)&Arow[k + 4];
        bf16x8 af = cvt8(a0, a1);
        #pragma unroll
        for (int t = 0; t < 3; ++t) {
            if (t < nT) {
                int nt = 4 * t + w;
                bf16x8 bf = *(const bf16x8*)&Bt[(long)(nt * 16 + ml) * 416 + k];
                acc[t] = __builtin_amdgcn_mfma_f32_16x16x32_bf16(af, bf, acc[t], 0, 0, 0);
            }
        }
    }

    #pragma unroll
    for (int t = 0; t < 3; ++t) {
        if (t < nT) {
            int nt = 4 * t + w;
            int col = nt * 16 + ml;
            float v0 = 0.f, v1 = 0.f, v2 = 0.f, v3 = 0.f;
            if (col < HID) {
                v0 = acc[t][0]; v1 = acc[t][1];
                v2 = acc[t][2]; v3 = acc[t][3];
            }
            *(uint2*)&PT[(long)col * TS + m0 + kg * 4] =
                make_uint2(pk2(v0, v1), pk2(v2, v3));
        }
    }
}

// ---------------------------------------------------------------------------
// span_all: grid (313, 5). Chunk x = 64 spans; 40 m-tiles of 16 (span,width)
// rows (rid = (n-1)*64 + i); block y owns m-tiles [8y, 8y+8), 2 per wave.
// Pooling + boundary concat + first layer = ONE banded MFMA GEMM:
//   h_pre = A @ [P; U; V],  K sections at k=0/96/160 (32-aligned),
//   A = softmax weights (bf16 e*invden) / 0-1 selectors, built in registers.
// n uniform per m-tile => only ~4-6 of 8 k-steps non-empty (banded skip).
// B-frags read straight from bf16-transposed UT/VT/PT (L2). Then the proven
// phase-2 MFMA (h @ W2) + relu-dot-W3 epilogue.
// ---------------------------------------------------------------------------
__global__ __launch_bounds__(256) void span_all(
    const short* __restrict__ UT, const short* __restrict__ VT,
    const short* __restrict__ PT, const float* __restrict__ logits,
    const short* __restrict__ W2t, const float* __restrict__ b2,
    const float* __restrict__ W3, const float* __restrict__ b3,
    float* __restrict__ out)
{
    __shared__ short h1s[4][16 * 168];
    __shared__ float ebuf[96];
    __shared__ float invden[640];
    __shared__ float Ls[80];
    __shared__ float b2s[160], W3s[160];

    const int tid = threadIdx.x;
    const int s0 = blockIdx.x * 64;
    const int y = blockIdx.y;

    if (tid < 80) {
        int r = s0 + tid; if (r > T_LEN - 1) r = T_LEN - 1;
        Ls[tid] = (tid < 73) ? logits[r] : -1e30f;
    }
    for (int t = tid; t < 160; t += 256) {
        b2s[t] = (t < HID) ? b2[t] : 0.f;
        W3s[t] = (t < HID) ? W3[t] : 0.f;
    }
    __syncthreads();
    if (tid < 96) {
        if (tid < 73) {
            float M = -1e30f;
            for (int t = 0; t < 73; ++t) M = fmaxf(M, Ls[t]);
            ebuf[tid] = expf(Ls[tid] - M);
        } else ebuf[tid] = 0.f;
    }
    __syncthreads();
    for (int t = tid; t < 640; t += 256) {
        int i = t & 63, nn = (t >> 6) + 1;
        float s = 0.f;
        for (int j = 0; j < nn; ++j) s += ebuf[i + j];
        invden[t] = 1.f / s;
    }
    __syncthreads();

    const int w = tid >> 6, lane = tid & 63;
    const int ml = lane & 15, kg = lane >> 4;
    short* hw = &h1s[w][0];

    for (int t2 = 0; t2 < 2; ++t2) {
        const int mt = y * 8 + w * 2 + t2;       // [0,40)
        const int n = (mt >> 2) + 1;
        const int i0 = (mt & 3) * 16;
        const int i = i0 + ml;
        const int iend = i + n - 1;
        const float invd = invden[mt * 16 + ml];

        f32x4 acc[10];
        #pragma unroll
        for (int nt = 0; nt < 10; ++nt) acc[nt] = (f32x4){0.f, 0.f, 0.f, 0.f};

        // --- P section (k in [0,96)): weights e[k]*invd inside [i, iend]
        {
            int kpa = i0 >> 5, kpb = (i0 + 14 + n) >> 5;
            for (int ks = kpa; ks <= kpb; ++ks) {
                int kb = ks * 32 + kg * 8;
                float v[8];
                #pragma unroll
                for (int x = 0; x < 8; ++x) {
                    int k = kb + x;
                    v[x] = (k >= i && k <= iend) ? ebuf[k] * invd : 0.f;
                }
                bf16x8 af = pack8(v);
                #pragma unroll
                for (int nt = 0; nt < 10; ++nt) {
                    bf16x8 bf = *(const bf16x8*)&PT[(long)(nt * 16 + ml) * TS + s0 + kb];
                    acc[nt] = __builtin_amdgcn_mfma_f32_16x16x32_bf16(af, bf, acc[nt], 0, 0, 0);
                }
            }
        }
        // --- U section (single k-step): selector (k == i)
        {
            int ks = i0 >> 5;
            int kb = ks * 32 + kg * 8;
            float v[8];
            #pragma unroll
            for (int x = 0; x < 8; ++x) v[x] = (kb + x == i) ? 1.f : 0.f;
            bf16x8 af = pack8(v);
            #pragma unroll
            for (int nt = 0; nt < 10; ++nt) {
                bf16x8 bf = *(const bf16x8*)&UT[(long)(nt * 16 + ml) * TS + s0 + kb];
                acc[nt] = __builtin_amdgcn_mfma_f32_16x16x32_bf16(af, bf, acc[nt], 0, 0, 0);
            }
        }
        // --- V section: selector (k == iend)
        {
            int kva = (i0 + n - 1) >> 5, kvb = (i0 + 14 + n) >> 5;
            for (int ks = kva; ks <= kvb; ++ks) {
                int kb = ks * 32 + kg * 8;
                float v[8];
                #pragma unroll
                for (int x = 0; x < 8; ++x) v[x] = (kb + x == iend) ? 1.f : 0.f;
                bf16x8 af = pack8(v);
                #pragma unroll
                for (int nt = 0; nt < 10; ++nt) {
                    bf16x8 bf = *(const bf16x8*)&VT[(long)(nt * 16 + ml) * TS + s0 + kb];
                    acc[nt] = __builtin_amdgcn_mfma_f32_16x16x32_bf16(af, bf, acc[nt], 0, 0, 0);
                }
            }
        }

        // --- h = relu(h_pre) -> bf16 wave-local LDS tile [16][168]
        #pragma unroll
        for (int nt = 0; nt < 10; ++nt) {
            int col = nt * 16 + ml;
            #pragma unroll
            for (int r = 0; r < 4; ++r)
                hw[(kg * 4 + r) * 168 + col] = f2bf(fmaxf(acc[nt][r], 0.f));
        }

        // --- phase 2: h @ W2 (K=160), epilogue relu-dot-W3
        bf16x8 af2[5];
        #pragma unroll
        for (int ks = 0; ks < 5; ++ks)
            af2[ks] = *(const bf16x8*)&hw[ml * 168 + ks * 32 + kg * 8];

        float score[4] = {0.f, 0.f, 0.f, 0.f};
        #pragma unroll
        for (int nt = 0; nt < 10; ++nt) {
            f32x4 a2 = {0.f, 0.f, 0.f, 0.f};
            #pragma unroll
            for (int ks = 0; ks < 5; ++ks) {
                bf16x8 bf = *(const bf16x8*)&W2t[(long)(nt * 16 + ml) * 168 + ks * 32 + kg * 8];
                a2 = __builtin_amdgcn_mfma_f32_16x16x32_bf16(af2[ks], bf, a2, 0, 0, 0);
            }
            int col = nt * 16 + ml;
            float b2v = b2s[col], w3v = W3s[col];
            #pragma unroll
            for (int r = 0; r < 4; ++r)
                score[r] += fmaxf(a2[r] + b2v, 0.f) * w3v;
        }
        #pragma unroll
        for (int r = 0; r < 4; ++r) {
            score[r] += __shfl_xor(score[r], 1);
            score[r] += __shfl_xor(score[r], 2);
            score[r] += __shfl_xor(score[r], 4);
            score[r] += __shfl_xor(score[r], 8);
        }
        if (ml == 0) {
            const int S = T_LEN - n + 1;
            const int out_off = (n - 1) * (T_LEN + 1) - (n - 1) * n / 2;
            float bb = b3[0];
            #pragma unroll
            for (int r = 0; r < 4; ++r) {
                int s = s0 + i0 + kg * 4 + r;
                if (s < S) out[out_off + s] = score[r] + bb;
            }
        }
    }
}

// ---------------------------------------------------------------------------
extern "C" void kernel_launch(void* const* d_in, const int* in_sizes, int n_in,
                              void* d_out, int out_size, void* d_ws, size_t ws_size,
                              hipStream_t stream) {
    const float* embeds  = (const float*)d_in[0];
    const float* states  = (const float*)d_in[1];
    const float* attn_W1 = (const float*)d_in[2];
    const float* attn_b1 = (const float*)d_in[3];
    const float* attn_W2 = (const float*)d_in[4];
    const float* attn_b2 = (const float*)d_in[5];
    const float* attn_W3 = (const float*)d_in[6];
    const float* attn_b3 = (const float*)d_in[7];
    const float* sc_W1   = (const float*)d_in[8];
    const float* sc_b1   = (const float*)d_in[9];
    const float* sc_W2   = (const float*)d_in[10];
    const float* sc_b2   = (const float*)d_in[11];
    const float* sc_W3   = (const float*)d_in[12];
    const float* sc_b3   = (const float*)d_in[13];
    float* out = (float*)d_out;

    short* wsS = (short*)d_ws;
    short* UT  = wsS;                         // [160][20000] bf16 + 256 slack
    short* VT  = wsS + 3200256;
    short* PT  = wsS + 6400512;
    short* wbf = wsS + 9600768;               // 318,720 shorts
    float* logits = (float*)(wsS + 9920000);  // 20,000 floats (byte ofs 19.84MB, 4-aligned)

    wprep<<<1245, 256, 0, stream>>>(sc_W1, attn_W1, attn_W2, sc_W2, wbf);
    fusedA<<<1250, 256, 0, stream>>>(states, wbf, sc_b1, attn_b1,
                                     attn_b2, attn_W3, attn_b3,
                                     UT, VT, logits);
    pkern<<<1250, 256, 0, stream>>>(embeds, wbf, PT);
    span_all<<<dim3(313, 5), 256, 0, stream>>>(UT, VT, PT, logits,
                                               wbf + 291840, sc_b2, sc_W3, sc_b3,
                                               out);
}

// Round 8
// 220.908 us; speedup vs baseline: 1.8820x; 1.8820x over previous
//
#include <hip/hip_runtime.h>
#include <hip/hip_bf16.h>
#include <math.h>

#define T_LEN 20000
#define HID 150

typedef __attribute__((ext_vector_type(8))) __bf16 bf16x8;
typedef __attribute__((ext_vector_type(4))) float f32x4;

__device__ __forceinline__ short f2bf(float f) {
    unsigned u = __float_as_uint(f);
    u = (u + 0x7fff + ((u >> 16) & 1)) >> 16;
    return (short)u;
}

__device__ __forceinline__ unsigned pk2(float a, float b) {
    __hip_bfloat162 h = __float22bfloat162_rn(make_float2(a, b));
    return *(unsigned*)&h;
}

__device__ __forceinline__ bf16x8 cvt8(float4 a, float4 b) {
    union { unsigned u[4]; bf16x8 v; } r;
    r.u[0] = pk2(a.x, a.y);
    r.u[1] = pk2(a.z, a.w);
    r.u[2] = pk2(b.x, b.y);
    r.u[3] = pk2(b.z, b.w);
    return r.v;
}

// unpack 2 bf16 (packed little-endian in a uint) -> 2 floats
__device__ __forceinline__ float2 ubf2(unsigned u) {
    return make_float2(__uint_as_float(u << 16),
                       __uint_as_float(u & 0xffff0000u));
}

// ---------------------------------------------------------------------------
// wprep: bf16 transposed weights (layout in shorts):
//   [0,66560)        Bt0 [160][416]  sc_W1 rows   0..399  (U)
//   [66560,133120)   Bt1 [160][416]  sc_W1 rows 400..799  (V)
//   [133120,199680)  At1 [160][416]  attn_W1
//   [199680,266240)  Bt2 [160][416]  sc_W1 rows 800..1099 (P, K=300)
//   [266240,291840)  At2 [160][160]  attn_W2
//   [291840,318720)  W2t [160][168]  sc_W2
// ---------------------------------------------------------------------------
__global__ __launch_bounds__(256) void wprep(
    const float* __restrict__ sc_W1, const float* __restrict__ attn_W1,
    const float* __restrict__ attn_W2, const float* __restrict__ sc_W2,
    short* __restrict__ wbf)
{
    int t = blockIdx.x * 256 + threadIdx.x;
    if (t >= 318720) return;
    float v = 0.f;
    if (t < 133120) {
        int y = t / 66560, r = t - y * 66560;
        int nn = r / 416, k = r - nn * 416;
        if (nn < HID && k < 400) v = sc_W1[(long)(y * 400 + k) * HID + nn];
    } else if (t < 199680) {
        int r = t - 133120;
        int nn = r / 416, k = r - nn * 416;
        if (nn < HID && k < 400) v = attn_W1[(long)k * HID + nn];
    } else if (t < 266240) {
        int r = t - 199680;
        int nn = r / 416, k = r - nn * 416;
        if (nn < HID && k < 300) v = sc_W1[(long)(800 + k) * HID + nn];
    } else if (t < 291840) {
        int r = t - 266240;
        int nn = r / 160, k = r - nn * 160;
        if (nn < HID && k < HID) v = attn_W2[(long)k * HID + nn];
    } else {
        int r = t - 291840;
        int nn = r / 168, k = r - nn * 168;
        if (nn < HID && k < HID) v = sc_W2[(long)k * HID + nn];
    }
    wbf[t] = f2bf(v);
}

// ---------------------------------------------------------------------------
// fusedA: 16 rows/block, grid 1250. One states pass -> Ubf, Vbf (bf16
// row-major [20000][160], sc_b1 folded into U, pad cols zeroed) + attn logits.
// 30 n-tiles split 8/8/7/7 across waves. MFMA operands SWAPPED
// (mfma(bf, af)): lane ml = token row, regs = 4 consecutive cols -> one
// packed 8B bf16x4 store per tile per lane (coalescing fix for r7's 2B mess).
// Attn tail (layer 2+3) unchanged from r6 (verified).
// ---------------------------------------------------------------------------
__global__ __launch_bounds__(256) void fusedA(
    const float* __restrict__ states, const short* __restrict__ wbf,
    const float* __restrict__ scb1, const float* __restrict__ ab1,
    const float* __restrict__ ab2, const float* __restrict__ aW3,
    const float* __restrict__ ab3,
    short* __restrict__ Ubf, short* __restrict__ Vbf, float* __restrict__ logits)
{
    __shared__ short h1s[16 * 168];
    __shared__ float red[16][4];
    __shared__ float sb1[160], ab1s[160];
    const int tid = threadIdx.x;
    const int w = tid >> 6, lane = tid & 63;
    const int ml = lane & 15, kg = lane >> 4;
    const int m0 = blockIdx.x * 16;          // 1250 * 16 = 20000 exact

    for (int t = tid; t < 160; t += 256) {
        sb1[t]  = (t < HID) ? scb1[t] : 0.f;
        ab1s[t] = (t < HID) ? ab1[t]  : 0.f;
    }
    __syncthreads();

    const float* Arow = states + (long)(m0 + ml) * 400;
    const int nT = (w < 2) ? 8 : 7;

    f32x4 acc[8];
    #pragma unroll
    for (int t = 0; t < 8; ++t) acc[t] = (f32x4){0.f, 0.f, 0.f, 0.f};

    for (int ks = 0; ks < 13; ++ks) {
        int k = ks * 32 + kg * 8;
        float4 a0 = make_float4(0.f, 0.f, 0.f, 0.f);
        float4 a1 = make_float4(0.f, 0.f, 0.f, 0.f);
        if (k + 4 <= 400) a0 = *(const float4*)&Arow[k];
        if (k + 8 <= 400) a1 = *(const float4*)&Arow[k + 4];
        bf16x8 af = cvt8(a0, a1);
        #pragma unroll
        for (int t = 0; t < 8; ++t) {
            if (t < nT) {
                int nt = 4 * t + w;
                bf16x8 bf = *(const bf16x8*)&wbf[(long)(nt * 16 + ml) * 416 + k];
                // swapped: D[lane ml = token][cols kg*4+r]
                acc[t] = __builtin_amdgcn_mfma_f32_16x16x32_bf16(bf, af, acc[t], 0, 0, 0);
            }
        }
    }

    #pragma unroll
    for (int t = 0; t < 8; ++t) {
        if (t < nT) {
            int nt = 4 * t + w;
            if (nt < 10) {                    // U (+sc_b1)
                int col0 = nt * 16 + kg * 4;
                float v[4];
                #pragma unroll
                for (int r = 0; r < 4; ++r) {
                    int c = col0 + r;
                    v[r] = (c < HID) ? acc[t][r] + sb1[c] : 0.f;
                }
                *(uint2*)&Ubf[(long)(m0 + ml) * 160 + col0] =
                    make_uint2(pk2(v[0], v[1]), pk2(v[2], v[3]));
            } else if (nt < 20) {             // V
                int col0 = (nt - 10) * 16 + kg * 4;
                float v[4];
                #pragma unroll
                for (int r = 0; r < 4; ++r) {
                    int c = col0 + r;
                    v[r] = (c < HID) ? acc[t][r] : 0.f;
                }
                *(uint2*)&Vbf[(long)(m0 + ml) * 160 + col0] =
                    make_uint2(pk2(v[0], v[1]), pk2(v[2], v[3]));
            } else {                          // X1 -> relu -> bf16 LDS
                int col0 = (nt - 20) * 16 + kg * 4;
                float v[4];
                #pragma unroll
                for (int r = 0; r < 4; ++r) {
                    int c = col0 + r;
                    v[r] = (c < HID) ? fmaxf(acc[t][r] + ab1s[c], 0.f) : 0.f;
                }
                *(uint2*)&h1s[ml * 168 + col0] =
                    make_uint2(pk2(v[0], v[1]), pk2(v[2], v[3]));
            }
        }
    }
    __syncthreads();

    // attn layer 2 (K=160) tiles split 3/3/2/2 + relu-dot-W3 epilogue
    const short* At2 = wbf + 266240;
    bf16x8 af2[5];
    #pragma unroll
    for (int ks = 0; ks < 5; ++ks)
        af2[ks] = *(const bf16x8*)&h1s[ml * 168 + ks * 32 + kg * 8];

    const int nT2 = (w < 2) ? 3 : 2;
    float score[4] = {0.f, 0.f, 0.f, 0.f};
    #pragma unroll
    for (int t = 0; t < 3; ++t) {
        if (t < nT2) {
            int nt = 4 * t + w;
            f32x4 a2 = {0.f, 0.f, 0.f, 0.f};
            #pragma unroll
            for (int ks = 0; ks < 5; ++ks) {
                bf16x8 bf = *(const bf16x8*)&At2[(long)(nt * 16 + ml) * 160 + ks * 32 + kg * 8];
                a2 = __builtin_amdgcn_mfma_f32_16x16x32_bf16(af2[ks], bf, a2, 0, 0, 0);
            }
            int col = nt * 16 + ml;
            float b2v = (col < HID) ? ab2[col] : 0.f;
            float w3v = (col < HID) ? aW3[col] : 0.f;
            #pragma unroll
            for (int r = 0; r < 4; ++r)
                score[r] += fmaxf(a2[r] + b2v, 0.f) * w3v;
        }
    }
    #pragma unroll
    for (int r = 0; r < 4; ++r) {
        score[r] += __shfl_xor(score[r], 1);
        score[r] += __shfl_xor(score[r], 2);
        score[r] += __shfl_xor(score[r], 4);
        score[r] += __shfl_xor(score[r], 8);
    }
    if (ml == 0) {
        #pragma unroll
        for (int r = 0; r < 4; ++r) red[kg * 4 + r][w] = score[r];
    }
    __syncthreads();
    if (tid < 16)
        logits[m0 + tid] = red[tid][0] + red[tid][1] + red[tid][2] + red[tid][3] + ab3[0];
}

// ---------------------------------------------------------------------------
// pkern: Pbf = bf16(embeds @ sc_W1[800:1100]) row-major [20000][160].
// 16 rows/block, grid 1250, tiles 3/3/2/2, swapped-operand MFMA + 8B stores.
// ---------------------------------------------------------------------------
__global__ __launch_bounds__(256) void pkern(
    const float* __restrict__ embeds, const short* __restrict__ wbf,
    short* __restrict__ Pbf)
{
    const int tid = threadIdx.x;
    const int w = tid >> 6, lane = tid & 63;
    const int ml = lane & 15, kg = lane >> 4;
    const int m0 = blockIdx.x * 16;
    const short* Bt = wbf + 199680;

    const float* Arow = embeds + (long)(m0 + ml) * 300;
    const int nT = (w < 2) ? 3 : 2;

    f32x4 acc[3];
    #pragma unroll
    for (int t = 0; t < 3; ++t) acc[t] = (f32x4){0.f, 0.f, 0.f, 0.f};

    for (int ks = 0; ks < 10; ++ks) {
        int k = ks * 32 + kg * 8;
        float4 a0 = make_float4(0.f, 0.f, 0.f, 0.f);
        float4 a1 = make_float4(0.f, 0.f, 0.f, 0.f);
        if (k + 4 <= 300) a0 = *(const float4*)&Arow[k];
        if (k + 8 <= 300) a1 = *(const float4*)&Arow[k + 4];
        bf16x8 af = cvt8(a0, a1);
        #pragma unroll
        for (int t = 0; t < 3; ++t) {
            if (t < nT) {
                int nt = 4 * t + w;
                bf16x8 bf = *(const bf16x8*)&Bt[(long)(nt * 16 + ml) * 416 + k];
                acc[t] = __builtin_amdgcn_mfma_f32_16x16x32_bf16(bf, af, acc[t], 0, 0, 0);
            }
        }
    }

    #pragma unroll
    for (int t = 0; t < 3; ++t) {
        if (t < nT) {
            int nt = 4 * t + w;
            int col0 = nt * 16 + kg * 4;
            float v[4];
            #pragma unroll
            for (int r = 0; r < 4; ++r) {
                int c = col0 + r;
                v[r] = (c < HID) ? acc[t][r] : 0.f;
            }
            *(uint2*)&Pbf[(long)(m0 + ml) * 160 + col0] =
                make_uint2(pk2(v[0], v[1]), pk2(v[2], v[3]));
        }
    }
}

// ---------------------------------------------------------------------------
// span_all: grid 625. 32 spans/block, ALL widths n=1..10 (incremental
// chunk-max softmax pooling, r5-verified). 8 threads/span x 20 dims:
// per-thread state Ur[20]+accp[20] (~half of r6's VGPRs). U/V/P are bf16
// row-major -> uint2 loads + unpack. Per n: h1 -> bf16 LDS [32][168], then
// 16x16x32 MFMA vs W2t (global, L2-resident): 2 m-tiles x 2 waves each
// (nt halves), partial relu-dot-W3 scores merged through LDS.
// ---------------------------------------------------------------------------
__global__ __launch_bounds__(256) void span_all(
    const short* __restrict__ Ubf, const short* __restrict__ Vbf,
    const short* __restrict__ Pbf, const float* __restrict__ logits,
    const short* __restrict__ W2t, const float* __restrict__ b2,
    const float* __restrict__ W3, const float* __restrict__ b3,
    float* __restrict__ out)
{
    __shared__ short h1s[32 * 168];     // 10752 B
    __shared__ float Ls[48], ebuf[48];
    __shared__ float b2s[160], W3s[160];
    __shared__ float red[32][2];

    const int tid = threadIdx.x;
    const int s0 = blockIdx.x * 32;

    if (tid < 48) {
        int r = s0 + tid; if (r > T_LEN - 1) r = T_LEN - 1;
        Ls[tid] = (tid < 41) ? logits[r] : -1e30f;
    }
    for (int t = tid; t < 160; t += 256) {
        b2s[t] = (t < HID) ? b2[t] : 0.f;
        W3s[t] = (t < HID) ? W3[t] : 0.f;
    }
    __syncthreads();
    if (tid < 48) {
        float M = -1e30f;
        for (int t = 0; t < 41; ++t) M = fmaxf(M, Ls[t]);
        ebuf[tid] = (tid < 41) ? expf(Ls[tid] - M) : 0.f;
    }
    __syncthreads();

    const int i = tid >> 3;       // span 0..31
    const int q = tid & 7;        // dim block [20q, 20q+20)
    const int d0 = 20 * q;
    const int s = s0 + i;
    int su = s; if (su > T_LEN - 1) su = T_LEN - 1;

    float Ur[20];
    {
        const uint2* U2 = (const uint2*)&Ubf[(long)su * 160 + d0];
        #pragma unroll
        for (int c = 0; c < 5; ++c) {
            uint2 uv = U2[c];
            float2 a = ubf2(uv.x), b_ = ubf2(uv.y);
            Ur[4 * c + 0] = a.x;  Ur[4 * c + 1] = a.y;
            Ur[4 * c + 2] = b_.x; Ur[4 * c + 3] = b_.y;
        }
    }
    float accp[20];
    #pragma unroll
    for (int d = 0; d < 20; ++d) accp[d] = 0.f;
    float den = 0.f;

    const int w = tid >> 6, lane = tid & 63;
    const int ml = lane & 15, kg = lane >> 4;
    const int mt = w >> 1;            // m-tile (spans mt*16..+15)
    const int nt0 = (w & 1) * 5;      // nt half
    const float bb = b3[0];

    for (int n = 1; n <= 10; ++n) {
        // --- phase 1: incremental pooled + h1 -> bf16 LDS
        int rr_ = s + n - 1; if (rr_ > T_LEN - 1) rr_ = T_LEN - 1;
        float e = ebuf[i + n - 1];
        den += e;
        {
            const uint2* P2 = (const uint2*)&Pbf[(long)rr_ * 160 + d0];
            #pragma unroll
            for (int c = 0; c < 5; ++c) {
                uint2 pv = P2[c];
                float2 a = ubf2(pv.x), b_ = ubf2(pv.y);
                accp[4 * c + 0] += e * a.x;  accp[4 * c + 1] += e * a.y;
                accp[4 * c + 2] += e * b_.x; accp[4 * c + 3] += e * b_.y;
            }
        }
        float invd = 1.f / den;
        {
            const uint2* V2 = (const uint2*)&Vbf[(long)rr_ * 160 + d0];
            #pragma unroll
            for (int c = 0; c < 5; ++c) {
                uint2 vv = V2[c];
                float2 a = ubf2(vv.x), b_ = ubf2(vv.y);
                float x0 = fmaxf(Ur[4 * c + 0] + a.x  + accp[4 * c + 0] * invd, 0.f);
                float x1 = fmaxf(Ur[4 * c + 1] + a.y  + accp[4 * c + 1] * invd, 0.f);
                float x2 = fmaxf(Ur[4 * c + 2] + b_.x + accp[4 * c + 2] * invd, 0.f);
                float x3 = fmaxf(Ur[4 * c + 3] + b_.y + accp[4 * c + 3] * invd, 0.f);
                *(uint2*)&h1s[i * 168 + d0 + 4 * c] =
                    make_uint2(pk2(x0, x1), pk2(x2, x3));
            }
        }
        __syncthreads();

        // --- phase 2: h1 @ W2 (K=160), epilogue relu-dot-W3
        bf16x8 af[5];
        #pragma unroll
        for (int ks = 0; ks < 5; ++ks)
            af[ks] = *(const bf16x8*)&h1s[(mt * 16 + ml) * 168 + ks * 32 + kg * 8];

        float sc[4] = {0.f, 0.f, 0.f, 0.f};
        #pragma unroll
        for (int j = 0; j < 5; ++j) {
            int nt = nt0 + j;
            f32x4 a2 = {0.f, 0.f, 0.f, 0.f};
            #pragma unroll
            for (int ks = 0; ks < 5; ++ks) {
                bf16x8 bf = *(const bf16x8*)&W2t[(long)(nt * 16 + ml) * 168 + ks * 32 + kg * 8];
                a2 = __builtin_amdgcn_mfma_f32_16x16x32_bf16(af[ks], bf, a2, 0, 0, 0);
            }
            int col = nt * 16 + ml;
            float b2v = b2s[col], w3v = W3s[col];
            #pragma unroll
            for (int r = 0; r < 4; ++r)
                sc[r] += fmaxf(a2[r] + b2v, 0.f) * w3v;
        }
        #pragma unroll
        for (int r = 0; r < 4; ++r) {
            sc[r] += __shfl_xor(sc[r], 1);
            sc[r] += __shfl_xor(sc[r], 2);
            sc[r] += __shfl_xor(sc[r], 4);
            sc[r] += __shfl_xor(sc[r], 8);
        }
        if (ml == 0) {
            #pragma unroll
            for (int r = 0; r < 4; ++r)
                red[mt * 16 + kg * 4 + r][w & 1] = sc[r];
        }
        __syncthreads();
        if (tid < 32) {
            int S = T_LEN - n + 1;
            int off = (n - 1) * (T_LEN + 1) - (n - 1) * n / 2;
            int sr = s0 + tid;
            if (sr < S) out[off + sr] = red[tid][0] + red[tid][1] + bb;
        }
        __syncthreads();   // before next n overwrites h1s / red
    }
}

// ---------------------------------------------------------------------------
extern "C" void kernel_launch(void* const* d_in, const int* in_sizes, int n_in,
                              void* d_out, int out_size, void* d_ws, size_t ws_size,
                              hipStream_t stream) {
    const float* embeds  = (const float*)d_in[0];
    const float* states  = (const float*)d_in[1];
    const float* attn_W1 = (const float*)d_in[2];
    const float* attn_b1 = (const float*)d_in[3];
    const float* attn_W2 = (const float*)d_in[4];
    const float* attn_b2 = (const float*)d_in[5];
    const float* attn_W3 = (const float*)d_in[6];
    const float* attn_b3 = (const float*)d_in[7];
    const float* sc_W1   = (const float*)d_in[8];
    const float* sc_b1   = (const float*)d_in[9];
    const float* sc_W2   = (const float*)d_in[10];
    const float* sc_b2   = (const float*)d_in[11];
    const float* sc_W3   = (const float*)d_in[12];
    const float* sc_b3   = (const float*)d_in[13];
    float* out = (float*)d_out;

    short* wsS = (short*)d_ws;
    short* Ubf = wsS;                         // [20000][160] bf16
    short* Vbf = wsS + 3200256;
    short* Pbf = wsS + 6400512;
    short* wbf = wsS + 9600768;               // 318,720 shorts
    float* logits = (float*)(wsS + 9920000);  // 20,000 floats

    wprep<<<1245, 256, 0, stream>>>(sc_W1, attn_W1, attn_W2, sc_W2, wbf);
    fusedA<<<1250, 256, 0, stream>>>(states, wbf, sc_b1, attn_b1,
                                     attn_b2, attn_W3, attn_b3,
                                     Ubf, Vbf, logits);
    pkern<<<1250, 256, 0, stream>>>(embeds, wbf, Pbf);
    span_all<<<625, 256, 0, stream>>>(Ubf, Vbf, Pbf, logits,
                                      wbf + 291840, sc_b2, sc_W3, sc_b3,
                                      out);
}

// Round 9
// 216.455 us; speedup vs baseline: 1.9207x; 1.0206x over previous
//
#include <hip/hip_runtime.h>
#include <hip/hip_bf16.h>
#include <math.h>

#define T_LEN 20000
#define HID 150

typedef __attribute__((ext_vector_type(8))) __bf16 bf16x8;
typedef __attribute__((ext_vector_type(4))) float f32x4;

__device__ __forceinline__ short f2bf(float f) {
    unsigned u = __float_as_uint(f);
    u = (u + 0x7fff + ((u >> 16) & 1)) >> 16;
    return (short)u;
}

__device__ __forceinline__ unsigned pk2(float a, float b) {
    __hip_bfloat162 h = __float22bfloat162_rn(make_float2(a, b));
    return *(unsigned*)&h;
}

__device__ __forceinline__ bf16x8 cvt8(float4 a, float4 b) {
    union { unsigned u[4]; bf16x8 v; } r;
    r.u[0] = pk2(a.x, a.y);
    r.u[1] = pk2(a.z, a.w);
    r.u[2] = pk2(b.x, b.y);
    r.u[3] = pk2(b.z, b.w);
    return r.v;
}

__device__ __forceinline__ float2 ubf2(unsigned u) {
    return make_float2(__uint_as_float(u << 16),
                       __uint_as_float(u & 0xffff0000u));
}

// ---------------------------------------------------------------------------
// Fragment-order weight regions (shorts), lane = consuming lane (ml|kg<<4):
//   fragA  [0,199680)        30 tiles x 13 ks x 64 x 8   U(0-9) V(10-19) aW1(20-29)
//   fragP  [199680,250880)   10 tiles x 10 ks x 64 x 8   sc_W1 rows 800..1099
//   fragAt2[250880,276480)   10 tiles x  5 ks x 64 x 8   attn_W2
//   fragW2 [276480,302080)   10 tiles x  5 ks x 64 x 8   sc_W2
// Element: frag[((tile*KS+ks)*64+lane)*8+e] = W[k=ks*32+(lane>>4)*8+e]
//                                              [col=tile*16+(lane&15)]
// -> every MFMA B-frag load is one coalesced 1KB wave transaction.
// ---------------------------------------------------------------------------
__global__ __launch_bounds__(256) void wprep(
    const float* __restrict__ sc_W1, const float* __restrict__ attn_W1,
    const float* __restrict__ attn_W2, const float* __restrict__ sc_W2,
    short* __restrict__ frag)
{
    int t = blockIdx.x * 256 + threadIdx.x;
    if (t >= 302080) return;
    float v = 0.f;
    if (t < 199680) {
        int e = t & 7, g = t >> 3;
        int lane = g & 63, h = g >> 6;
        int ks = h % 13, nt = h / 13;
        int k = ks * 32 + (lane >> 4) * 8 + e;
        int cs = (nt % 10) * 16 + (lane & 15);
        if (k < 400 && cs < HID) {
            if (nt < 10)      v = sc_W1[(long)k * HID + cs];
            else if (nt < 20) v = sc_W1[(long)(400 + k) * HID + cs];
            else              v = attn_W1[(long)k * HID + cs];
        }
    } else if (t < 250880) {
        int r = t - 199680;
        int e = r & 7, g = r >> 3;
        int lane = g & 63, h = g >> 6;
        int ks = h % 10, nt = h / 10;
        int k = ks * 32 + (lane >> 4) * 8 + e;
        int cs = nt * 16 + (lane & 15);
        if (k < 300 && cs < HID) v = sc_W1[(long)(800 + k) * HID + cs];
    } else if (t < 276480) {
        int r = t - 250880;
        int e = r & 7, g = r >> 3;
        int lane = g & 63, h = g >> 6;
        int ks = h % 5, nt = h / 5;
        int k = ks * 32 + (lane >> 4) * 8 + e;
        int cs = nt * 16 + (lane & 15);
        if (k < HID && cs < HID) v = attn_W2[(long)k * HID + cs];
    } else {
        int r = t - 276480;
        int e = r & 7, g = r >> 3;
        int lane = g & 63, h = g >> 6;
        int ks = h % 5, nt = h / 5;
        int k = ks * 32 + (lane >> 4) * 8 + e;
        int cs = nt * 16 + (lane & 15);
        if (k < HID && cs < HID) v = sc_W2[(long)k * HID + cs];
    }
    frag[t] = f2bf(v);
}

// ---------------------------------------------------------------------------
// fusedA: 32 rows/block, grid 625. One states pass -> Ubf, Vbf (bf16 row-major
// [20000][160], sc_b1 folded into U) + attn logits. 30 n-tiles split 8/8/7/7
// across waves; each weight frag (coalesced 1KB load) feeds 2 MFMAs (two
// 16-row m-tiles). Swapped-operand MFMA (r8-verified): lane ml = token,
// regs = 4 consecutive cols -> packed 8B stores.
// ---------------------------------------------------------------------------
__global__ __launch_bounds__(256) void fusedA(
    const float* __restrict__ states, const short* __restrict__ frag,
    const float* __restrict__ scb1, const float* __restrict__ ab1,
    const float* __restrict__ ab2, const float* __restrict__ aW3,
    const float* __restrict__ ab3,
    short* __restrict__ Ubf, short* __restrict__ Vbf, float* __restrict__ logits)
{
    __shared__ short h1s[32 * 168];
    __shared__ float red[32][4];
    __shared__ float sb1[160], ab1s[160];
    const int tid = threadIdx.x;
    const int w = tid >> 6, lane = tid & 63;
    const int ml = lane & 15, kg = lane >> 4;
    const int m0 = blockIdx.x * 32;          // 625 * 32 = 20000 exact

    for (int t = tid; t < 160; t += 256) {
        sb1[t]  = (t < HID) ? scb1[t] : 0.f;
        ab1s[t] = (t < HID) ? ab1[t]  : 0.f;
    }
    __syncthreads();

    const float* Arow0 = states + (long)(m0 + ml) * 400;
    const float* Arow1 = states + (long)(m0 + 16 + ml) * 400;
    const int nT = (w < 2) ? 8 : 7;

    f32x4 acc0[8], acc1[8];
    #pragma unroll
    for (int t = 0; t < 8; ++t) {
        acc0[t] = (f32x4){0.f, 0.f, 0.f, 0.f};
        acc1[t] = (f32x4){0.f, 0.f, 0.f, 0.f};
    }

    for (int ks = 0; ks < 13; ++ks) {
        int k = ks * 32 + kg * 8;
        float4 a0 = make_float4(0.f, 0.f, 0.f, 0.f), a1 = a0, b0 = a0, b1 = a0;
        if (k + 4 <= 400) { a0 = *(const float4*)&Arow0[k]; b0 = *(const float4*)&Arow1[k]; }
        if (k + 8 <= 400) { a1 = *(const float4*)&Arow0[k + 4]; b1 = *(const float4*)&Arow1[k + 4]; }
        bf16x8 af0 = cvt8(a0, a1);
        bf16x8 af1 = cvt8(b0, b1);
        #pragma unroll
        for (int t = 0; t < 8; ++t) {
            if (t < nT) {
                int nt = 4 * t + w;
                bf16x8 bf = *(const bf16x8*)&frag[(long)(((nt * 13 + ks) << 6) | lane) << 3];
                acc0[t] = __builtin_amdgcn_mfma_f32_16x16x32_bf16(bf, af0, acc0[t], 0, 0, 0);
                acc1[t] = __builtin_amdgcn_mfma_f32_16x16x32_bf16(bf, af1, acc1[t], 0, 0, 0);
            }
        }
    }

    #pragma unroll
    for (int t = 0; t < 8; ++t) {
        if (t < nT) {
            int nt = 4 * t + w;
            if (nt < 10) {                    // U (+sc_b1)
                int col0 = nt * 16 + kg * 4;
                float v0[4], v1[4];
                #pragma unroll
                for (int r = 0; r < 4; ++r) {
                    int c = col0 + r;
                    v0[r] = (c < HID) ? acc0[t][r] + sb1[c] : 0.f;
                    v1[r] = (c < HID) ? acc1[t][r] + sb1[c] : 0.f;
                }
                *(uint2*)&Ubf[(long)(m0 + ml) * 160 + col0] =
                    make_uint2(pk2(v0[0], v0[1]), pk2(v0[2], v0[3]));
                *(uint2*)&Ubf[(long)(m0 + 16 + ml) * 160 + col0] =
                    make_uint2(pk2(v1[0], v1[1]), pk2(v1[2], v1[3]));
            } else if (nt < 20) {             // V
                int col0 = (nt - 10) * 16 + kg * 4;
                float v0[4], v1[4];
                #pragma unroll
                for (int r = 0; r < 4; ++r) {
                    int c = col0 + r;
                    v0[r] = (c < HID) ? acc0[t][r] : 0.f;
                    v1[r] = (c < HID) ? acc1[t][r] : 0.f;
                }
                *(uint2*)&Vbf[(long)(m0 + ml) * 160 + col0] =
                    make_uint2(pk2(v0[0], v0[1]), pk2(v0[2], v0[3]));
                *(uint2*)&Vbf[(long)(m0 + 16 + ml) * 160 + col0] =
                    make_uint2(pk2(v1[0], v1[1]), pk2(v1[2], v1[3]));
            } else {                          // X1 -> relu -> bf16 LDS
                int col0 = (nt - 20) * 16 + kg * 4;
                float v0[4], v1[4];
                #pragma unroll
                for (int r = 0; r < 4; ++r) {
                    int c = col0 + r;
                    v0[r] = (c < HID) ? fmaxf(acc0[t][r] + ab1s[c], 0.f) : 0.f;
                    v1[r] = (c < HID) ? fmaxf(acc1[t][r] + ab1s[c], 0.f) : 0.f;
                }
                *(uint2*)&h1s[ml * 168 + col0] =
                    make_uint2(pk2(v0[0], v0[1]), pk2(v0[2], v0[3]));
                *(uint2*)&h1s[(16 + ml) * 168 + col0] =
                    make_uint2(pk2(v1[0], v1[1]), pk2(v1[2], v1[3]));
            }
        }
    }
    __syncthreads();

    // attn layer 2 (K=160): tiles split 3/3/2/2, both m-tiles per wave
    const short* fAt2 = frag + 250880;
    bf16x8 af2a[5], af2b[5];
    #pragma unroll
    for (int ks = 0; ks < 5; ++ks) {
        af2a[ks] = *(const bf16x8*)&h1s[ml * 168 + ks * 32 + kg * 8];
        af2b[ks] = *(const bf16x8*)&h1s[(16 + ml) * 168 + ks * 32 + kg * 8];
    }

    const int nT2 = (w < 2) ? 3 : 2;
    float sca[4] = {0.f, 0.f, 0.f, 0.f}, scb[4] = {0.f, 0.f, 0.f, 0.f};
    #pragma unroll
    for (int t = 0; t < 3; ++t) {
        if (t < nT2) {
            int nt = 4 * t + w;
            f32x4 a2 = {0.f, 0.f, 0.f, 0.f}, b2_ = {0.f, 0.f, 0.f, 0.f};
            #pragma unroll
            for (int ks = 0; ks < 5; ++ks) {
                bf16x8 bf = *(const bf16x8*)&fAt2[(long)(((nt * 5 + ks) << 6) | lane) << 3];
                a2  = __builtin_amdgcn_mfma_f32_16x16x32_bf16(af2a[ks], bf, a2, 0, 0, 0);
                b2_ = __builtin_amdgcn_mfma_f32_16x16x32_bf16(af2b[ks], bf, b2_, 0, 0, 0);
            }
            int col = nt * 16 + ml;
            float b2v = (col < HID) ? ab2[col] : 0.f;
            float w3v = (col < HID) ? aW3[col] : 0.f;
            #pragma unroll
            for (int r = 0; r < 4; ++r) {
                sca[r] += fmaxf(a2[r] + b2v, 0.f) * w3v;
                scb[r] += fmaxf(b2_[r] + b2v, 0.f) * w3v;
            }
        }
    }
    #pragma unroll
    for (int r = 0; r < 4; ++r) {
        sca[r] += __shfl_xor(sca[r], 1); scb[r] += __shfl_xor(scb[r], 1);
        sca[r] += __shfl_xor(sca[r], 2); scb[r] += __shfl_xor(scb[r], 2);
        sca[r] += __shfl_xor(sca[r], 4); scb[r] += __shfl_xor(scb[r], 4);
        sca[r] += __shfl_xor(sca[r], 8); scb[r] += __shfl_xor(scb[r], 8);
    }
    if (ml == 0) {
        #pragma unroll
        for (int r = 0; r < 4; ++r) {
            red[kg * 4 + r][w] = sca[r];
            red[16 + kg * 4 + r][w] = scb[r];
        }
    }
    __syncthreads();
    if (tid < 32)
        logits[m0 + tid] = red[tid][0] + red[tid][1] + red[tid][2] + red[tid][3] + ab3[0];
}

// ---------------------------------------------------------------------------
// pkern: Pbf = bf16(embeds @ sc_W1[800:1100]) row-major [20000][160].
// 32 rows/block, grid 625, tiles 3/3/2/2, coalesced frag loads, 2 m-tiles.
// ---------------------------------------------------------------------------
__global__ __launch_bounds__(256) void pkern(
    const float* __restrict__ embeds, const short* __restrict__ frag,
    short* __restrict__ Pbf)
{
    const int tid = threadIdx.x;
    const int w = tid >> 6, lane = tid & 63;
    const int ml = lane & 15, kg = lane >> 4;
    const int m0 = blockIdx.x * 32;
    const short* fP = frag + 199680;

    const float* Arow0 = embeds + (long)(m0 + ml) * 300;
    const float* Arow1 = embeds + (long)(m0 + 16 + ml) * 300;
    const int nT = (w < 2) ? 3 : 2;

    f32x4 acc0[3], acc1[3];
    #pragma unroll
    for (int t = 0; t < 3; ++t) {
        acc0[t] = (f32x4){0.f, 0.f, 0.f, 0.f};
        acc1[t] = (f32x4){0.f, 0.f, 0.f, 0.f};
    }

    for (int ks = 0; ks < 10; ++ks) {
        int k = ks * 32 + kg * 8;
        float4 a0 = make_float4(0.f, 0.f, 0.f, 0.f), a1 = a0, b0 = a0, b1 = a0;
        if (k + 4 <= 300) { a0 = *(const float4*)&Arow0[k]; b0 = *(const float4*)&Arow1[k]; }
        if (k + 8 <= 300) { a1 = *(const float4*)&Arow0[k + 4]; b1 = *(const float4*)&Arow1[k + 4]; }
        bf16x8 af0 = cvt8(a0, a1);
        bf16x8 af1 = cvt8(b0, b1);
        #pragma unroll
        for (int t = 0; t < 3; ++t) {
            if (t < nT) {
                int nt = 4 * t + w;
                bf16x8 bf = *(const bf16x8*)&fP[(long)(((nt * 10 + ks) << 6) | lane) << 3];
                acc0[t] = __builtin_amdgcn_mfma_f32_16x16x32_bf16(bf, af0, acc0[t], 0, 0, 0);
                acc1[t] = __builtin_amdgcn_mfma_f32_16x16x32_bf16(bf, af1, acc1[t], 0, 0, 0);
            }
        }
    }

    #pragma unroll
    for (int t = 0; t < 3; ++t) {
        if (t < nT) {
            int nt = 4 * t + w;
            int col0 = nt * 16 + kg * 4;
            float v0[4], v1[4];
            #pragma unroll
            for (int r = 0; r < 4; ++r) {
                int c = col0 + r;
                v0[r] = (c < HID) ? acc0[t][r] : 0.f;
                v1[r] = (c < HID) ? acc1[t][r] : 0.f;
            }
            *(uint2*)&Pbf[(long)(m0 + ml) * 160 + col0] =
                make_uint2(pk2(v0[0], v0[1]), pk2(v0[2], v0[3]));
            *(uint2*)&Pbf[(long)(m0 + 16 + ml) * 160 + col0] =
                make_uint2(pk2(v1[0], v1[1]), pk2(v1[2], v1[3]));
        }
    }
}

// ---------------------------------------------------------------------------
// span_all: grid 625, 32 spans/block, all widths n=1..10 (incremental
// chunk-max softmax, r5/r8-verified). 8 threads/span x 20 dims. Phase 2:
// 16x16x32 MFMA vs fragment-order fragW2 (coalesced 1KB loads).
// ---------------------------------------------------------------------------
__global__ __launch_bounds__(256) void span_all(
    const short* __restrict__ Ubf, const short* __restrict__ Vbf,
    const short* __restrict__ Pbf, const float* __restrict__ logits,
    const short* __restrict__ fW2, const float* __restrict__ b2,
    const float* __restrict__ W3, const float* __restrict__ b3,
    float* __restrict__ out)
{
    __shared__ short h1s[32 * 168];
    __shared__ float Ls[48], ebuf[48];
    __shared__ float b2s[160], W3s[160];
    __shared__ float red[32][2];

    const int tid = threadIdx.x;
    const int s0 = blockIdx.x * 32;

    if (tid < 48) {
        int r = s0 + tid; if (r > T_LEN - 1) r = T_LEN - 1;
        Ls[tid] = (tid < 41) ? logits[r] : -1e30f;
    }
    for (int t = tid; t < 160; t += 256) {
        b2s[t] = (t < HID) ? b2[t] : 0.f;
        W3s[t] = (t < HID) ? W3[t] : 0.f;
    }
    __syncthreads();
    if (tid < 48) {
        float M = -1e30f;
        for (int t = 0; t < 41; ++t) M = fmaxf(M, Ls[t]);
        ebuf[tid] = (tid < 41) ? expf(Ls[tid] - M) : 0.f;
    }
    __syncthreads();

    const int i = tid >> 3;       // span 0..31
    const int q = tid & 7;        // dim block [20q, 20q+20)
    const int d0 = 20 * q;
    const int s = s0 + i;
    int su = s; if (su > T_LEN - 1) su = T_LEN - 1;

    float Ur[20];
    {
        const uint2* U2 = (const uint2*)&Ubf[(long)su * 160 + d0];
        #pragma unroll
        for (int c = 0; c < 5; ++c) {
            uint2 uv = U2[c];
            float2 a = ubf2(uv.x), b_ = ubf2(uv.y);
            Ur[4 * c + 0] = a.x;  Ur[4 * c + 1] = a.y;
            Ur[4 * c + 2] = b_.x; Ur[4 * c + 3] = b_.y;
        }
    }
    float accp[20];
    #pragma unroll
    for (int d = 0; d < 20; ++d) accp[d] = 0.f;
    float den = 0.f;

    const int w = tid >> 6, lane = tid & 63;
    const int ml = lane & 15, kg = lane >> 4;
    const int mt = w >> 1;            // m-tile (spans mt*16..+15)
    const int nt0 = (w & 1) * 5;      // nt half
    const float bb = b3[0];

    for (int n = 1; n <= 10; ++n) {
        int rr_ = s + n - 1; if (rr_ > T_LEN - 1) rr_ = T_LEN - 1;
        float e = ebuf[i + n - 1];
        den += e;
        {
            const uint2* P2 = (const uint2*)&Pbf[(long)rr_ * 160 + d0];
            #pragma unroll
            for (int c = 0; c < 5; ++c) {
                uint2 pv = P2[c];
                float2 a = ubf2(pv.x), b_ = ubf2(pv.y);
                accp[4 * c + 0] += e * a.x;  accp[4 * c + 1] += e * a.y;
                accp[4 * c + 2] += e * b_.x; accp[4 * c + 3] += e * b_.y;
            }
        }
        float invd = 1.f / den;
        {
            const uint2* V2 = (const uint2*)&Vbf[(long)rr_ * 160 + d0];
            #pragma unroll
            for (int c = 0; c < 5; ++c) {
                uint2 vv = V2[c];
                float2 a = ubf2(vv.x), b_ = ubf2(vv.y);
                float x0 = fmaxf(Ur[4 * c + 0] + a.x  + accp[4 * c + 0] * invd, 0.f);
                float x1 = fmaxf(Ur[4 * c + 1] + a.y  + accp[4 * c + 1] * invd, 0.f);
                float x2 = fmaxf(Ur[4 * c + 2] + b_.x + accp[4 * c + 2] * invd, 0.f);
                float x3 = fmaxf(Ur[4 * c + 3] + b_.y + accp[4 * c + 3] * invd, 0.f);
                *(uint2*)&h1s[i * 168 + d0 + 4 * c] =
                    make_uint2(pk2(x0, x1), pk2(x2, x3));
            }
        }
        __syncthreads();

        bf16x8 af[5];
        #pragma unroll
        for (int ks = 0; ks < 5; ++ks)
            af[ks] = *(const bf16x8*)&h1s[(mt * 16 + ml) * 168 + ks * 32 + kg * 8];

        float sc[4] = {0.f, 0.f, 0.f, 0.f};
        #pragma unroll
        for (int j = 0; j < 5; ++j) {
            int nt = nt0 + j;
            f32x4 a2 = {0.f, 0.f, 0.f, 0.f};
            #pragma unroll
            for (int ks = 0; ks < 5; ++ks) {
                bf16x8 bf = *(const bf16x8*)&fW2[(long)(((nt * 5 + ks) << 6) | lane) << 3];
                a2 = __builtin_amdgcn_mfma_f32_16x16x32_bf16(af[ks], bf, a2, 0, 0, 0);
            }
            int col = nt * 16 + ml;
            float b2v = b2s[col], w3v = W3s[col];
            #pragma unroll
            for (int r = 0; r < 4; ++r)
                sc[r] += fmaxf(a2[r] + b2v, 0.f) * w3v;
        }
        #pragma unroll
        for (int r = 0; r < 4; ++r) {
            sc[r] += __shfl_xor(sc[r], 1);
            sc[r] += __shfl_xor(sc[r], 2);
            sc[r] += __shfl_xor(sc[r], 4);
            sc[r] += __shfl_xor(sc[r], 8);
        }
        if (ml == 0) {
            #pragma unroll
            for (int r = 0; r < 4; ++r)
                red[mt * 16 + kg * 4 + r][w & 1] = sc[r];
        }
        __syncthreads();
        if (tid < 32) {
            int S = T_LEN - n + 1;
            int off = (n - 1) * (T_LEN + 1) - (n - 1) * n / 2;
            int sr = s0 + tid;
            if (sr < S) out[off + sr] = red[tid][0] + red[tid][1] + bb;
        }
        __syncthreads();
    }
}

// ---------------------------------------------------------------------------
extern "C" void kernel_launch(void* const* d_in, const int* in_sizes, int n_in,
                              void* d_out, int out_size, void* d_ws, size_t ws_size,
                              hipStream_t stream) {
    const float* embeds  = (const float*)d_in[0];
    const float* states  = (const float*)d_in[1];
    const float* attn_W1 = (const float*)d_in[2];
    const float* attn_b1 = (const float*)d_in[3];
    const float* attn_W2 = (const float*)d_in[4];
    const float* attn_b2 = (const float*)d_in[5];
    const float* attn_W3 = (const float*)d_in[6];
    const float* attn_b3 = (const float*)d_in[7];
    const float* sc_W1   = (const float*)d_in[8];
    const float* sc_b1   = (const float*)d_in[9];
    const float* sc_W2   = (const float*)d_in[10];
    const float* sc_b2   = (const float*)d_in[11];
    const float* sc_W3   = (const float*)d_in[12];
    const float* sc_b3   = (const float*)d_in[13];
    float* out = (float*)d_out;

    short* wsS = (short*)d_ws;
    short* Ubf = wsS;                         // [20000][160] bf16
    short* Vbf = wsS + 3200256;
    short* Pbf = wsS + 6400512;
    short* frag = wsS + 9600768;              // 302,080 shorts
    float* logits = (float*)(wsS + 9902848);  // 20,000 floats

    wprep<<<1180, 256, 0, stream>>>(sc_W1, attn_W1, attn_W2, sc_W2, frag);
    fusedA<<<625, 256, 0, stream>>>(states, frag, sc_b1, attn_b1,
                                    attn_b2, attn_W3, attn_b3,
                                    Ubf, Vbf, logits);
    pkern<<<625, 256, 0, stream>>>(embeds, frag, Pbf);
    span_all<<<625, 256, 0, stream>>>(Ubf, Vbf, Pbf, logits,
                                      frag + 276480, sc_b2, sc_W3, sc_b3,
                                      out);
}

// Round 10
// 200.022 us; speedup vs baseline: 2.0785x; 1.0822x over previous
//
#include <hip/hip_runtime.h>
#include <hip/hip_bf16.h>
#include <math.h>

#define T_LEN 20000
#define HID 150

typedef __attribute__((ext_vector_type(8))) __bf16 bf16x8;
typedef __attribute__((ext_vector_type(4))) float f32x4;

__device__ __forceinline__ short f2bf(float f) {
    unsigned u = __float_as_uint(f);
    u = (u + 0x7fff + ((u >> 16) & 1)) >> 16;
    return (short)u;
}

__device__ __forceinline__ unsigned pk2(float a, float b) {
    __hip_bfloat162 h = __float22bfloat162_rn(make_float2(a, b));
    return *(unsigned*)&h;
}

__device__ __forceinline__ bf16x8 cvt8(float4 a, float4 b) {
    union { unsigned u[4]; bf16x8 v; } r;
    r.u[0] = pk2(a.x, a.y);
    r.u[1] = pk2(a.z, a.w);
    r.u[2] = pk2(b.x, b.y);
    r.u[3] = pk2(b.z, b.w);
    return r.v;
}

__device__ __forceinline__ float2 ubf2(unsigned u) {
    return make_float2(__uint_as_float(u << 16),
                       __uint_as_float(u & 0xffff0000u));
}

// ---------------------------------------------------------------------------
// Fragment-order weight regions (shorts), lane = consuming lane (ml|kg<<4):
//   fragA  [0,199680)        30 tiles x 13 ks x 64 x 8   U(0-9) V(10-19) aW1(20-29)
//   fragP  [199680,250880)   10 tiles x 10 ks x 64 x 8   sc_W1 rows 800..1099
//   fragAt2[250880,276480)   10 tiles x  5 ks x 64 x 8   attn_W2
//   fragW2 [276480,302080)   10 tiles x  5 ks x 64 x 8   sc_W2
// frag[((tile*KS+ks)*64+lane)*8+e] = W[k=ks*32+(lane>>4)*8+e][col=tile*16+(lane&15)]
// -> every MFMA B-frag load is one coalesced 1KB wave transaction.
// ---------------------------------------------------------------------------
__global__ __launch_bounds__(256) void wprep(
    const float* __restrict__ sc_W1, const float* __restrict__ attn_W1,
    const float* __restrict__ attn_W2, const float* __restrict__ sc_W2,
    short* __restrict__ frag)
{
    int t = blockIdx.x * 256 + threadIdx.x;
    if (t >= 302080) return;
    float v = 0.f;
    if (t < 199680) {
        int e = t & 7, g = t >> 3;
        int lane = g & 63, h = g >> 6;
        int ks = h % 13, nt = h / 13;
        int k = ks * 32 + (lane >> 4) * 8 + e;
        int cs = (nt % 10) * 16 + (lane & 15);
        if (k < 400 && cs < HID) {
            if (nt < 10)      v = sc_W1[(long)k * HID + cs];
            else if (nt < 20) v = sc_W1[(long)(400 + k) * HID + cs];
            else              v = attn_W1[(long)k * HID + cs];
        }
    } else if (t < 250880) {
        int r = t - 199680;
        int e = r & 7, g = r >> 3;
        int lane = g & 63, h = g >> 6;
        int ks = h % 10, nt = h / 10;
        int k = ks * 32 + (lane >> 4) * 8 + e;
        int cs = nt * 16 + (lane & 15);
        if (k < 300 && cs < HID) v = sc_W1[(long)(800 + k) * HID + cs];
    } else if (t < 276480) {
        int r = t - 250880;
        int e = r & 7, g = r >> 3;
        int lane = g & 63, h = g >> 6;
        int ks = h % 5, nt = h / 5;
        int k = ks * 32 + (lane >> 4) * 8 + e;
        int cs = nt * 16 + (lane & 15);
        if (k < HID && cs < HID) v = attn_W2[(long)k * HID + cs];
    } else {
        int r = t - 276480;
        int e = r & 7, g = r >> 3;
        int lane = g & 63, h = g >> 6;
        int ks = h % 5, nt = h / 5;
        int k = ks * 32 + (lane >> 4) * 8 + e;
        int cs = nt * 16 + (lane & 15);
        if (k < HID && cs < HID) v = sc_W2[(long)k * HID + cs];
    }
    frag[t] = f2bf(v);
}

// ---------------------------------------------------------------------------
// fusedA: 16 rows/block, grid 1250 (r8's width) + coalesced frag loads (r9).
// One states pass -> Ubf, Vbf (bf16 row-major [20000][160], sc_b1 folded into
// U) + attn logits. 30 n-tiles split 8/8/7/7 across waves. Swapped-operand
// MFMA: lane ml = token, regs = 4 consecutive cols -> packed 8B stores.
// ---------------------------------------------------------------------------
__global__ __launch_bounds__(256) void fusedA(
    const float* __restrict__ states, const short* __restrict__ frag,
    const float* __restrict__ scb1, const float* __restrict__ ab1,
    const float* __restrict__ ab2, const float* __restrict__ aW3,
    const float* __restrict__ ab3,
    short* __restrict__ Ubf, short* __restrict__ Vbf, float* __restrict__ logits)
{
    __shared__ short h1s[16 * 168];
    __shared__ float red[16][4];
    __shared__ float sb1[160], ab1s[160];
    const int tid = threadIdx.x;
    const int w = tid >> 6, lane = tid & 63;
    const int ml = lane & 15, kg = lane >> 4;
    const int m0 = blockIdx.x * 16;          // 1250 * 16 = 20000 exact

    for (int t = tid; t < 160; t += 256) {
        sb1[t]  = (t < HID) ? scb1[t] : 0.f;
        ab1s[t] = (t < HID) ? ab1[t]  : 0.f;
    }
    __syncthreads();

    const float* Arow = states + (long)(m0 + ml) * 400;
    const int nT = (w < 2) ? 8 : 7;

    f32x4 acc[8];
    #pragma unroll
    for (int t = 0; t < 8; ++t) acc[t] = (f32x4){0.f, 0.f, 0.f, 0.f};

    for (int ks = 0; ks < 13; ++ks) {
        int k = ks * 32 + kg * 8;
        float4 a0 = make_float4(0.f, 0.f, 0.f, 0.f);
        float4 a1 = make_float4(0.f, 0.f, 0.f, 0.f);
        if (k + 4 <= 400) a0 = *(const float4*)&Arow[k];
        if (k + 8 <= 400) a1 = *(const float4*)&Arow[k + 4];
        bf16x8 af = cvt8(a0, a1);
        #pragma unroll
        for (int t = 0; t < 8; ++t) {
            if (t < nT) {
                int nt = 4 * t + w;
                bf16x8 bf = *(const bf16x8*)&frag[(long)(((nt * 13 + ks) << 6) | lane) << 3];
                acc[t] = __builtin_amdgcn_mfma_f32_16x16x32_bf16(bf, af, acc[t], 0, 0, 0);
            }
        }
    }

    #pragma unroll
    for (int t = 0; t < 8; ++t) {
        if (t < nT) {
            int nt = 4 * t + w;
            if (nt < 10) {                    // U (+sc_b1)
                int col0 = nt * 16 + kg * 4;
                float v[4];
                #pragma unroll
                for (int r = 0; r < 4; ++r) {
                    int c = col0 + r;
                    v[r] = (c < HID) ? acc[t][r] + sb1[c] : 0.f;
                }
                *(uint2*)&Ubf[(long)(m0 + ml) * 160 + col0] =
                    make_uint2(pk2(v[0], v[1]), pk2(v[2], v[3]));
            } else if (nt < 20) {             // V
                int col0 = (nt - 10) * 16 + kg * 4;
                float v[4];
                #pragma unroll
                for (int r = 0; r < 4; ++r) {
                    int c = col0 + r;
                    v[r] = (c < HID) ? acc[t][r] : 0.f;
                }
                *(uint2*)&Vbf[(long)(m0 + ml) * 160 + col0] =
                    make_uint2(pk2(v[0], v[1]), pk2(v[2], v[3]));
            } else {                          // X1 -> relu -> bf16 LDS
                int col0 = (nt - 20) * 16 + kg * 4;
                float v[4];
                #pragma unroll
                for (int r = 0; r < 4; ++r) {
                    int c = col0 + r;
                    v[r] = (c < HID) ? fmaxf(acc[t][r] + ab1s[c], 0.f) : 0.f;
                }
                *(uint2*)&h1s[ml * 168 + col0] =
                    make_uint2(pk2(v[0], v[1]), pk2(v[2], v[3]));
            }
        }
    }
    __syncthreads();

    // attn layer 2 (K=160) tiles split 3/3/2/2 + relu-dot-W3 epilogue
    const short* fAt2 = frag + 250880;
    bf16x8 af2[5];
    #pragma unroll
    for (int ks = 0; ks < 5; ++ks)
        af2[ks] = *(const bf16x8*)&h1s[ml * 168 + ks * 32 + kg * 8];

    const int nT2 = (w < 2) ? 3 : 2;
    float score[4] = {0.f, 0.f, 0.f, 0.f};
    #pragma unroll
    for (int t = 0; t < 3; ++t) {
        if (t < nT2) {
            int nt = 4 * t + w;
            f32x4 a2 = {0.f, 0.f, 0.f, 0.f};
            #pragma unroll
            for (int ks = 0; ks < 5; ++ks) {
                bf16x8 bf = *(const bf16x8*)&fAt2[(long)(((nt * 5 + ks) << 6) | lane) << 3];
                a2 = __builtin_amdgcn_mfma_f32_16x16x32_bf16(af2[ks], bf, a2, 0, 0, 0);
            }
            int col = nt * 16 + ml;
            float b2v = (col < HID) ? ab2[col] : 0.f;
            float w3v = (col < HID) ? aW3[col] : 0.f;
            #pragma unroll
            for (int r = 0; r < 4; ++r)
                score[r] += fmaxf(a2[r] + b2v, 0.f) * w3v;
        }
    }
    #pragma unroll
    for (int r = 0; r < 4; ++r) {
        score[r] += __shfl_xor(score[r], 1);
        score[r] += __shfl_xor(score[r], 2);
        score[r] += __shfl_xor(score[r], 4);
        score[r] += __shfl_xor(score[r], 8);
    }
    if (ml == 0) {
        #pragma unroll
        for (int r = 0; r < 4; ++r) red[kg * 4 + r][w] = score[r];
    }
    __syncthreads();
    if (tid < 16)
        logits[m0 + tid] = red[tid][0] + red[tid][1] + red[tid][2] + red[tid][3] + ab3[0];
}

// ---------------------------------------------------------------------------
// pkern: Pbf = bf16(embeds @ sc_W1[800:1100]) row-major [20000][160].
// 16 rows/block, grid 1250, tiles 3/3/2/2, coalesced frag loads.
// ---------------------------------------------------------------------------
__global__ __launch_bounds__(256) void pkern(
    const float* __restrict__ embeds, const short* __restrict__ frag,
    short* __restrict__ Pbf)
{
    const int tid = threadIdx.x;
    const int w = tid >> 6, lane = tid & 63;
    const int ml = lane & 15, kg = lane >> 4;
    const int m0 = blockIdx.x * 16;
    const short* fP = frag + 199680;

    const float* Arow = embeds + (long)(m0 + ml) * 300;
    const int nT = (w < 2) ? 3 : 2;

    f32x4 acc[3];
    #pragma unroll
    for (int t = 0; t < 3; ++t) acc[t] = (f32x4){0.f, 0.f, 0.f, 0.f};

    for (int ks = 0; ks < 10; ++ks) {
        int k = ks * 32 + kg * 8;
        float4 a0 = make_float4(0.f, 0.f, 0.f, 0.f);
        float4 a1 = make_float4(0.f, 0.f, 0.f, 0.f);
        if (k + 4 <= 300) a0 = *(const float4*)&Arow[k];
        if (k + 8 <= 300) a1 = *(const float4*)&Arow[k + 4];
        bf16x8 af = cvt8(a0, a1);
        #pragma unroll
        for (int t = 0; t < 3; ++t) {
            if (t < nT) {
                int nt = 4 * t + w;
                bf16x8 bf = *(const bf16x8*)&fP[(long)(((nt * 10 + ks) << 6) | lane) << 3];
                acc[t] = __builtin_amdgcn_mfma_f32_16x16x32_bf16(bf, af, acc[t], 0, 0, 0);
            }
        }
    }

    #pragma unroll
    for (int t = 0; t < 3; ++t) {
        if (t < nT) {
            int nt = 4 * t + w;
            int col0 = nt * 16 + kg * 4;
            float v[4];
            #pragma unroll
            for (int r = 0; r < 4; ++r) {
                int c = col0 + r;
                v[r] = (c < HID) ? acc[t][r] : 0.f;
            }
            *(uint2*)&Pbf[(long)(m0 + ml) * 160 + col0] =
                make_uint2(pk2(v[0], v[1]), pk2(v[2], v[3]));
        }
    }
}

// ---------------------------------------------------------------------------
// span_all: grid (625, 2). Block (x,y): 32 spans of chunk x, widths
// n in {1..5} (y=0) or {6..10} (y=1, with 5-row L2-hit prefix).
// 8 threads/span x 20 dims incremental chunk-max softmax pooling (r8-verified);
// phase 2: 16x16x32 MFMA vs fragment-order fragW2 (coalesced 1KB loads).
// ---------------------------------------------------------------------------
__global__ __launch_bounds__(256) void span_all(
    const short* __restrict__ Ubf, const short* __restrict__ Vbf,
    const short* __restrict__ Pbf, const float* __restrict__ logits,
    const short* __restrict__ fW2, const float* __restrict__ b2,
    const float* __restrict__ W3, const float* __restrict__ b3,
    float* __restrict__ out)
{
    __shared__ short h1s[32 * 168];
    __shared__ float Ls[48], ebuf[48];
    __shared__ float b2s[160], W3s[160];
    __shared__ float red[32][2];

    const int tid = threadIdx.x;
    const int s0 = blockIdx.x * 32;
    const int nlo = blockIdx.y ? 6 : 1;
    const int nhi = blockIdx.y ? 10 : 5;

    if (tid < 48) {
        int r = s0 + tid; if (r > T_LEN - 1) r = T_LEN - 1;
        Ls[tid] = (tid < 41) ? logits[r] : -1e30f;
    }
    for (int t = tid; t < 160; t += 256) {
        b2s[t] = (t < HID) ? b2[t] : 0.f;
        W3s[t] = (t < HID) ? W3[t] : 0.f;
    }
    __syncthreads();
    if (tid < 48) {
        float M = -1e30f;
        for (int t = 0; t < 41; ++t) M = fmaxf(M, Ls[t]);
        ebuf[tid] = (tid < 41) ? expf(Ls[tid] - M) : 0.f;
    }
    __syncthreads();

    const int i = tid >> 3;       // span 0..31
    const int q = tid & 7;        // dim block [20q, 20q+20)
    const int d0 = 20 * q;
    const int s = s0 + i;
    int su = s; if (su > T_LEN - 1) su = T_LEN - 1;

    float Ur[20];
    {
        const uint2* U2 = (const uint2*)&Ubf[(long)su * 160 + d0];
        #pragma unroll
        for (int c = 0; c < 5; ++c) {
            uint2 uv = U2[c];
            float2 a = ubf2(uv.x), b_ = ubf2(uv.y);
            Ur[4 * c + 0] = a.x;  Ur[4 * c + 1] = a.y;
            Ur[4 * c + 2] = b_.x; Ur[4 * c + 3] = b_.y;
        }
    }
    float accp[20];
    #pragma unroll
    for (int d = 0; d < 20; ++d) accp[d] = 0.f;
    float den = 0.f;

    // prefix j = 0..nlo-2 (only y=1: 5 rows, L2-hit)
    for (int j = 0; j < nlo - 1; ++j) {
        int rr_ = s + j; if (rr_ > T_LEN - 1) rr_ = T_LEN - 1;
        float e = ebuf[i + j];
        den += e;
        const uint2* P2 = (const uint2*)&Pbf[(long)rr_ * 160 + d0];
        #pragma unroll
        for (int c = 0; c < 5; ++c) {
            uint2 pv = P2[c];
            float2 a = ubf2(pv.x), b_ = ubf2(pv.y);
            accp[4 * c + 0] += e * a.x;  accp[4 * c + 1] += e * a.y;
            accp[4 * c + 2] += e * b_.x; accp[4 * c + 3] += e * b_.y;
        }
    }

    const int w = tid >> 6, lane = tid & 63;
    const int ml = lane & 15, kg = lane >> 4;
    const int mt = w >> 1;            // m-tile (spans mt*16..+15)
    const int nt0 = (w & 1) * 5;      // nt half
    const float bb = b3[0];

    for (int n = nlo; n <= nhi; ++n) {
        int rr_ = s + n - 1; if (rr_ > T_LEN - 1) rr_ = T_LEN - 1;
        float e = ebuf[i + n - 1];
        den += e;
        {
            const uint2* P2 = (const uint2*)&Pbf[(long)rr_ * 160 + d0];
            #pragma unroll
            for (int c = 0; c < 5; ++c) {
                uint2 pv = P2[c];
                float2 a = ubf2(pv.x), b_ = ubf2(pv.y);
                accp[4 * c + 0] += e * a.x;  accp[4 * c + 1] += e * a.y;
                accp[4 * c + 2] += e * b_.x; accp[4 * c + 3] += e * b_.y;
            }
        }
        float invd = 1.f / den;
        {
            const uint2* V2 = (const uint2*)&Vbf[(long)rr_ * 160 + d0];
            #pragma unroll
            for (int c = 0; c < 5; ++c) {
                uint2 vv = V2[c];
                float2 a = ubf2(vv.x), b_ = ubf2(vv.y);
                float x0 = fmaxf(Ur[4 * c + 0] + a.x  + accp[4 * c + 0] * invd, 0.f);
                float x1 = fmaxf(Ur[4 * c + 1] + a.y  + accp[4 * c + 1] * invd, 0.f);
                float x2 = fmaxf(Ur[4 * c + 2] + b_.x + accp[4 * c + 2] * invd, 0.f);
                float x3 = fmaxf(Ur[4 * c + 3] + b_.y + accp[4 * c + 3] * invd, 0.f);
                *(uint2*)&h1s[i * 168 + d0 + 4 * c] =
                    make_uint2(pk2(x0, x1), pk2(x2, x3));
            }
        }
        __syncthreads();

        bf16x8 af[5];
        #pragma unroll
        for (int ks = 0; ks < 5; ++ks)
            af[ks] = *(const bf16x8*)&h1s[(mt * 16 + ml) * 168 + ks * 32 + kg * 8];

        float sc[4] = {0.f, 0.f, 0.f, 0.f};
        #pragma unroll
        for (int j = 0; j < 5; ++j) {
            int nt = nt0 + j;
            f32x4 a2 = {0.f, 0.f, 0.f, 0.f};
            #pragma unroll
            for (int ks = 0; ks < 5; ++ks) {
                bf16x8 bf = *(const bf16x8*)&fW2[(long)(((nt * 5 + ks) << 6) | lane) << 3];
                a2 = __builtin_amdgcn_mfma_f32_16x16x32_bf16(af[ks], bf, a2, 0, 0, 0);
            }
            int col = nt * 16 + ml;
            float b2v = b2s[col], w3v = W3s[col];
            #pragma unroll
            for (int r = 0; r < 4; ++r)
                sc[r] += fmaxf(a2[r] + b2v, 0.f) * w3v;
        }
        #pragma unroll
        for (int r = 0; r < 4; ++r) {
            sc[r] += __shfl_xor(sc[r], 1);
            sc[r] += __shfl_xor(sc[r], 2);
            sc[r] += __shfl_xor(sc[r], 4);
            sc[r] += __shfl_xor(sc[r], 8);
        }
        if (ml == 0) {
            #pragma unroll
            for (int r = 0; r < 4; ++r)
                red[mt * 16 + kg * 4 + r][w & 1] = sc[r];
        }
        __syncthreads();
        if (tid < 32) {
            int S = T_LEN - n + 1;
            int off = (n - 1) * (T_LEN + 1) - (n - 1) * n / 2;
            int sr = s0 + tid;
            if (sr < S) out[off + sr] = red[tid][0] + red[tid][1] + bb;
        }
        __syncthreads();
    }
}

// ---------------------------------------------------------------------------
extern "C" void kernel_launch(void* const* d_in, const int* in_sizes, int n_in,
                              void* d_out, int out_size, void* d_ws, size_t ws_size,
                              hipStream_t stream) {
    const float* embeds  = (const float*)d_in[0];
    const float* states  = (const float*)d_in[1];
    const float* attn_W1 = (const float*)d_in[2];
    const float* attn_b1 = (const float*)d_in[3];
    const float* attn_W2 = (const float*)d_in[4];
    const float* attn_b2 = (const float*)d_in[5];
    const float* attn_W3 = (const float*)d_in[6];
    const float* attn_b3 = (const float*)d_in[7];
    const float* sc_W1   = (const float*)d_in[8];
    const float* sc_b1   = (const float*)d_in[9];
    const float* sc_W2   = (const float*)d_in[10];
    const float* sc_b2   = (const float*)d_in[11];
    const float* sc_W3   = (const float*)d_in[12];
    const float* sc_b3   = (const float*)d_in[13];
    float* out = (float*)d_out;

    short* wsS = (short*)d_ws;
    short* Ubf = wsS;                         // [20000][160] bf16
    short* Vbf = wsS + 3200256;
    short* Pbf = wsS + 6400512;
    short* frag = wsS + 9600768;              // 302,080 shorts
    float* logits = (float*)(wsS + 9902848);  // 20,000 floats

    wprep<<<1180, 256, 0, stream>>>(sc_W1, attn_W1, attn_W2, sc_W2, frag);
    fusedA<<<1250, 256, 0, stream>>>(states, frag, sc_b1, attn_b1,
                                     attn_b2, attn_W3, attn_b3,
                                     Ubf, Vbf, logits);
    pkern<<<1250, 256, 0, stream>>>(embeds, frag, Pbf);
    span_all<<<dim3(625, 2), 256, 0, stream>>>(Ubf, Vbf, Pbf, logits,
                                               frag + 276480, sc_b2, sc_W3, sc_b3,
                                               out);
}

// Round 11
// 191.508 us; speedup vs baseline: 2.1709x; 1.0445x over previous
//
#include <hip/hip_runtime.h>
#include <hip/hip_bf16.h>
#include <math.h>

#define T_LEN 20000
#define HID 150

typedef __attribute__((ext_vector_type(8))) __bf16 bf16x8;
typedef __attribute__((ext_vector_type(4))) float f32x4;

__device__ __forceinline__ short f2bf(float f) {
    unsigned u = __float_as_uint(f);
    u = (u + 0x7fff + ((u >> 16) & 1)) >> 16;
    return (short)u;
}

__device__ __forceinline__ unsigned pk2(float a, float b) {
    __hip_bfloat162 h = __float22bfloat162_rn(make_float2(a, b));
    return *(unsigned*)&h;
}

__device__ __forceinline__ bf16x8 cvt8(float4 a, float4 b) {
    union { unsigned u[4]; bf16x8 v; } r;
    r.u[0] = pk2(a.x, a.y);
    r.u[1] = pk2(a.z, a.w);
    r.u[2] = pk2(b.x, b.y);
    r.u[3] = pk2(b.z, b.w);
    return r.v;
}

__device__ __forceinline__ float2 ubf2(unsigned u) {
    return make_float2(__uint_as_float(u << 16),
                       __uint_as_float(u & 0xffff0000u));
}

// ---------------------------------------------------------------------------
// Fragment-order weight regions (shorts), lane = consuming lane (ml|kg<<4):
//   fragA  [0,199680)        30 tiles x 13 ks x 64 x 8   U(0-9) V(10-19) aW1(20-29)
//   fragP  [199680,250880)   10 tiles x 10 ks x 64 x 8   sc_W1 rows 800..1099
//   fragAt2[250880,276480)   10 tiles x  5 ks x 64 x 8   attn_W2
//   fragW2 [276480,302080)   10 tiles x  5 ks x 64 x 8   sc_W2
// frag[((tile*KS+ks)*64+lane)*8+e] = W[k=ks*32+(lane>>4)*8+e][col=tile*16+(lane&15)]
// ---------------------------------------------------------------------------
__global__ __launch_bounds__(256) void wprep(
    const float* __restrict__ sc_W1, const float* __restrict__ attn_W1,
    const float* __restrict__ attn_W2, const float* __restrict__ sc_W2,
    short* __restrict__ frag)
{
    int t = blockIdx.x * 256 + threadIdx.x;
    if (t >= 302080) return;
    float v = 0.f;
    if (t < 199680) {
        int e = t & 7, g = t >> 3;
        int lane = g & 63, h = g >> 6;
        int ks = h % 13, nt = h / 13;
        int k = ks * 32 + (lane >> 4) * 8 + e;
        int cs = (nt % 10) * 16 + (lane & 15);
        if (k < 400 && cs < HID) {
            if (nt < 10)      v = sc_W1[(long)k * HID + cs];
            else if (nt < 20) v = sc_W1[(long)(400 + k) * HID + cs];
            else              v = attn_W1[(long)k * HID + cs];
        }
    } else if (t < 250880) {
        int r = t - 199680;
        int e = r & 7, g = r >> 3;
        int lane = g & 63, h = g >> 6;
        int ks = h % 10, nt = h / 10;
        int k = ks * 32 + (lane >> 4) * 8 + e;
        int cs = nt * 16 + (lane & 15);
        if (k < 300 && cs < HID) v = sc_W1[(long)(800 + k) * HID + cs];
    } else if (t < 276480) {
        int r = t - 250880;
        int e = r & 7, g = r >> 3;
        int lane = g & 63, h = g >> 6;
        int ks = h % 5, nt = h / 5;
        int k = ks * 32 + (lane >> 4) * 8 + e;
        int cs = nt * 16 + (lane & 15);
        if (k < HID && cs < HID) v = attn_W2[(long)k * HID + cs];
    } else {
        int r = t - 276480;
        int e = r & 7, g = r >> 3;
        int lane = g & 63, h = g >> 6;
        int ks = h % 5, nt = h / 5;
        int k = ks * 32 + (lane >> 4) * 8 + e;
        int cs = nt * 16 + (lane & 15);
        if (k < HID && cs < HID) v = sc_W2[(long)k * HID + cs];
    }
    frag[t] = f2bf(v);
}

// ---------------------------------------------------------------------------
// fusedAP: 16 rows/block, grid 1250. Merges r10's fusedA + pkern:
//   Phase A: states pass (K=400, 30 tiles 8/8/7/7) -> Ubf, Vbf, X1(LDS)
//   Phase B: embeds pass (K=300, 10 tiles 3/3/2/2)  -> Pbf
//   Phase C: attn layers 2/3 -> logits
// All ks loops fully unrolled (immediate-offset frag addressing). Swapped-
// operand MFMA: lane ml = token, regs = 4 consecutive cols -> 8B stores.
// ---------------------------------------------------------------------------
__global__ __launch_bounds__(256) void fusedAP(
    const float* __restrict__ states, const float* __restrict__ embeds,
    const short* __restrict__ frag,
    const float* __restrict__ scb1, const float* __restrict__ ab1,
    const float* __restrict__ ab2, const float* __restrict__ aW3,
    const float* __restrict__ ab3,
    short* __restrict__ Ubf, short* __restrict__ Vbf, short* __restrict__ Pbf,
    float* __restrict__ logits)
{
    __shared__ short h1s[16 * 168];
    __shared__ float red[16][4];
    __shared__ float sb1[160], ab1s[160];
    const int tid = threadIdx.x;
    const int w = tid >> 6, lane = tid & 63;
    const int ml = lane & 15, kg = lane >> 4;
    const int m0 = blockIdx.x * 16;          // 1250 * 16 = 20000 exact

    for (int t = tid; t < 160; t += 256) {
        sb1[t]  = (t < HID) ? scb1[t] : 0.f;
        ab1s[t] = (t < HID) ? ab1[t]  : 0.f;
    }
    __syncthreads();

    // ---------------- Phase A: states @ {U,V,aW1} ----------------
    const float* Arow = states + (long)(m0 + ml) * 400;
    const int nT = (w < 2) ? 8 : 7;

    f32x4 acc[8];
    #pragma unroll
    for (int t = 0; t < 8; ++t) acc[t] = (f32x4){0.f, 0.f, 0.f, 0.f};

    #pragma unroll
    for (int ks = 0; ks < 13; ++ks) {
        int k = ks * 32 + kg * 8;
        float4 a0 = make_float4(0.f, 0.f, 0.f, 0.f);
        float4 a1 = make_float4(0.f, 0.f, 0.f, 0.f);
        if (k + 4 <= 400) a0 = *(const float4*)&Arow[k];
        if (k + 8 <= 400) a1 = *(const float4*)&Arow[k + 4];
        bf16x8 af = cvt8(a0, a1);
        #pragma unroll
        for (int t = 0; t < 8; ++t) {
            if (t < nT) {
                int nt = 4 * t + w;
                bf16x8 bf = *(const bf16x8*)&frag[(long)(((nt * 13 + ks) << 6) | lane) << 3];
                acc[t] = __builtin_amdgcn_mfma_f32_16x16x32_bf16(bf, af, acc[t], 0, 0, 0);
            }
        }
    }

    #pragma unroll
    for (int t = 0; t < 8; ++t) {
        if (t < nT) {
            int nt = 4 * t + w;
            if (nt < 10) {                    // U (+sc_b1)
                int col0 = nt * 16 + kg * 4;
                float v[4];
                #pragma unroll
                for (int r = 0; r < 4; ++r) {
                    int c = col0 + r;
                    v[r] = (c < HID) ? acc[t][r] + sb1[c] : 0.f;
                }
                *(uint2*)&Ubf[(long)(m0 + ml) * 160 + col0] =
                    make_uint2(pk2(v[0], v[1]), pk2(v[2], v[3]));
            } else if (nt < 20) {             // V
                int col0 = (nt - 10) * 16 + kg * 4;
                float v[4];
                #pragma unroll
                for (int r = 0; r < 4; ++r) {
                    int c = col0 + r;
                    v[r] = (c < HID) ? acc[t][r] : 0.f;
                }
                *(uint2*)&Vbf[(long)(m0 + ml) * 160 + col0] =
                    make_uint2(pk2(v[0], v[1]), pk2(v[2], v[3]));
            } else {                          // X1 -> relu -> bf16 LDS
                int col0 = (nt - 20) * 16 + kg * 4;
                float v[4];
                #pragma unroll
                for (int r = 0; r < 4; ++r) {
                    int c = col0 + r;
                    v[r] = (c < HID) ? fmaxf(acc[t][r] + ab1s[c], 0.f) : 0.f;
                }
                *(uint2*)&h1s[ml * 168 + col0] =
                    make_uint2(pk2(v[0], v[1]), pk2(v[2], v[3]));
            }
        }
    }
    __syncthreads();

    // ---------------- Phase B: embeds @ P-slice (pkern merged) ----------------
    {
        const short* fP = frag + 199680;
        const float* Erow = embeds + (long)(m0 + ml) * 300;
        const int nTp = (w < 2) ? 3 : 2;
        f32x4 accP[3];
        #pragma unroll
        for (int t = 0; t < 3; ++t) accP[t] = (f32x4){0.f, 0.f, 0.f, 0.f};

        #pragma unroll
        for (int ks = 0; ks < 10; ++ks) {
            int k = ks * 32 + kg * 8;
            float4 a0 = make_float4(0.f, 0.f, 0.f, 0.f);
            float4 a1 = make_float4(0.f, 0.f, 0.f, 0.f);
            if (k + 4 <= 300) a0 = *(const float4*)&Erow[k];
            if (k + 8 <= 300) a1 = *(const float4*)&Erow[k + 4];
            bf16x8 af = cvt8(a0, a1);
            #pragma unroll
            for (int t = 0; t < 3; ++t) {
                if (t < nTp) {
                    int nt = 4 * t + w;
                    bf16x8 bf = *(const bf16x8*)&fP[(long)(((nt * 10 + ks) << 6) | lane) << 3];
                    accP[t] = __builtin_amdgcn_mfma_f32_16x16x32_bf16(bf, af, accP[t], 0, 0, 0);
                }
            }
        }

        #pragma unroll
        for (int t = 0; t < 3; ++t) {
            if (t < nTp) {
                int nt = 4 * t + w;
                int col0 = nt * 16 + kg * 4;
                float v[4];
                #pragma unroll
                for (int r = 0; r < 4; ++r) {
                    int c = col0 + r;
                    v[r] = (c < HID) ? accP[t][r] : 0.f;
                }
                *(uint2*)&Pbf[(long)(m0 + ml) * 160 + col0] =
                    make_uint2(pk2(v[0], v[1]), pk2(v[2], v[3]));
            }
        }
    }

    // ---------------- Phase C: attn layers 2+3 ----------------
    const short* fAt2 = frag + 250880;
    bf16x8 af2[5];
    #pragma unroll
    for (int ks = 0; ks < 5; ++ks)
        af2[ks] = *(const bf16x8*)&h1s[ml * 168 + ks * 32 + kg * 8];

    const int nT2 = (w < 2) ? 3 : 2;
    float score[4] = {0.f, 0.f, 0.f, 0.f};
    #pragma unroll
    for (int t = 0; t < 3; ++t) {
        if (t < nT2) {
            int nt = 4 * t + w;
            f32x4 a2 = {0.f, 0.f, 0.f, 0.f};
            #pragma unroll
            for (int ks = 0; ks < 5; ++ks) {
                bf16x8 bf = *(const bf16x8*)&fAt2[(long)(((nt * 5 + ks) << 6) | lane) << 3];
                a2 = __builtin_amdgcn_mfma_f32_16x16x32_bf16(af2[ks], bf, a2, 0, 0, 0);
            }
            int col = nt * 16 + ml;
            float b2v = (col < HID) ? ab2[col] : 0.f;
            float w3v = (col < HID) ? aW3[col] : 0.f;
            #pragma unroll
            for (int r = 0; r < 4; ++r)
                score[r] += fmaxf(a2[r] + b2v, 0.f) * w3v;
        }
    }
    #pragma unroll
    for (int r = 0; r < 4; ++r) {
        score[r] += __shfl_xor(score[r], 1);
        score[r] += __shfl_xor(score[r], 2);
        score[r] += __shfl_xor(score[r], 4);
        score[r] += __shfl_xor(score[r], 8);
    }
    if (ml == 0) {
        #pragma unroll
        for (int r = 0; r < 4; ++r) red[kg * 4 + r][w] = score[r];
    }
    __syncthreads();
    if (tid < 16)
        logits[m0 + tid] = red[tid][0] + red[tid][1] + red[tid][2] + red[tid][3] + ab3[0];
}

// ---------------------------------------------------------------------------
// span_all: grid (625, 2). Block (x,y): 32 spans of chunk x, widths n in
// {1..5} (y=0) or {6..10} (y=1, 5-row L2-hit prefix). SOFTWARE-PIPELINED:
// double-buffered h1s/red, phase1(n+1) overlaps phase2(n), ONE sync per n.
// ---------------------------------------------------------------------------
__global__ __launch_bounds__(256) void span_all(
    const short* __restrict__ Ubf, const short* __restrict__ Vbf,
    const short* __restrict__ Pbf, const float* __restrict__ logits,
    const short* __restrict__ fW2, const float* __restrict__ b2,
    const float* __restrict__ W3, const float* __restrict__ b3,
    float* __restrict__ out)
{
    __shared__ short h1s[2][32 * 168];
    __shared__ float red[2][32][2];
    __shared__ float Ls[48], ebuf[48];
    __shared__ float b2s[160], W3s[160];

    const int tid = threadIdx.x;
    const int s0 = blockIdx.x * 32;
    const int nlo = blockIdx.y ? 6 : 1;
    const int nhi = blockIdx.y ? 10 : 5;

    if (tid < 48) {
        int r = s0 + tid; if (r > T_LEN - 1) r = T_LEN - 1;
        Ls[tid] = (tid < 41) ? logits[r] : -1e30f;
    }
    for (int t = tid; t < 160; t += 256) {
        b2s[t] = (t < HID) ? b2[t] : 0.f;
        W3s[t] = (t < HID) ? W3[t] : 0.f;
    }
    __syncthreads();
    if (tid < 48) {
        float M = -1e30f;
        for (int t = 0; t < 41; ++t) M = fmaxf(M, Ls[t]);
        ebuf[tid] = (tid < 41) ? expf(Ls[tid] - M) : 0.f;
    }
    __syncthreads();

    const int i = tid >> 3;       // span 0..31
    const int q = tid & 7;        // dim block [20q, 20q+20)
    const int d0 = 20 * q;
    const int s = s0 + i;
    int su = s; if (su > T_LEN - 1) su = T_LEN - 1;

    float Ur[20];
    {
        const uint2* U2 = (const uint2*)&Ubf[(long)su * 160 + d0];
        #pragma unroll
        for (int c = 0; c < 5; ++c) {
            uint2 uv = U2[c];
            float2 a = ubf2(uv.x), b_ = ubf2(uv.y);
            Ur[4 * c + 0] = a.x;  Ur[4 * c + 1] = a.y;
            Ur[4 * c + 2] = b_.x; Ur[4 * c + 3] = b_.y;
        }
    }
    float accp[20];
    #pragma unroll
    for (int d = 0; d < 20; ++d) accp[d] = 0.f;
    float den = 0.f;

    // prefix j = 0..nlo-2 (only y=1: 5 rows, L2-hit)
    for (int j = 0; j < nlo - 1; ++j) {
        int rr_ = s + j; if (rr_ > T_LEN - 1) rr_ = T_LEN - 1;
        float e = ebuf[i + j];
        den += e;
        const uint2* P2 = (const uint2*)&Pbf[(long)rr_ * 160 + d0];
        #pragma unroll
        for (int c = 0; c < 5; ++c) {
            uint2 pv = P2[c];
            float2 a = ubf2(pv.x), b_ = ubf2(pv.y);
            accp[4 * c + 0] += e * a.x;  accp[4 * c + 1] += e * a.y;
            accp[4 * c + 2] += e * b_.x; accp[4 * c + 3] += e * b_.y;
        }
    }

    const int w = tid >> 6, lane = tid & 63;
    const int ml = lane & 15, kg = lane >> 4;
    const int mt = w >> 1;            // m-tile (spans mt*16..+15)
    const int nt0 = (w & 1) * 5;      // nt half
    const float bb = b3[0];

    // phase1 for n: update accp/den, write h1 -> h1s[p]
    auto phase1 = [&](int n, int p) {
        int rr_ = s + n - 1; if (rr_ > T_LEN - 1) rr_ = T_LEN - 1;
        float e = ebuf[i + n - 1];
        den += e;
        {
            const uint2* P2 = (const uint2*)&Pbf[(long)rr_ * 160 + d0];
            #pragma unroll
            for (int c = 0; c < 5; ++c) {
                uint2 pv = P2[c];
                float2 a = ubf2(pv.x), b_ = ubf2(pv.y);
                accp[4 * c + 0] += e * a.x;  accp[4 * c + 1] += e * a.y;
                accp[4 * c + 2] += e * b_.x; accp[4 * c + 3] += e * b_.y;
            }
        }
        float invd = 1.f / den;
        {
            const uint2* V2 = (const uint2*)&Vbf[(long)rr_ * 160 + d0];
            #pragma unroll
            for (int c = 0; c < 5; ++c) {
                uint2 vv = V2[c];
                float2 a = ubf2(vv.x), b_ = ubf2(vv.y);
                float x0 = fmaxf(Ur[4 * c + 0] + a.x  + accp[4 * c + 0] * invd, 0.f);
                float x1 = fmaxf(Ur[4 * c + 1] + a.y  + accp[4 * c + 1] * invd, 0.f);
                float x2 = fmaxf(Ur[4 * c + 2] + b_.x + accp[4 * c + 2] * invd, 0.f);
                float x3 = fmaxf(Ur[4 * c + 3] + b_.y + accp[4 * c + 3] * invd, 0.f);
                *(uint2*)&h1s[p][i * 168 + d0 + 4 * c] =
                    make_uint2(pk2(x0, x1), pk2(x2, x3));
            }
        }
    };

    phase1(nlo, 0);
    __syncthreads();

    for (int n = nlo; n <= nhi; ++n) {
        const int p = (n - nlo) & 1;
        // phase 1 for n+1 into the other buffer (overlaps phase 2's MFMAs)
        if (n < nhi) phase1(n + 1, 1 - p);

        // phase 2 on h1s[p]
        bf16x8 af[5];
        #pragma unroll
        for (int ks = 0; ks < 5; ++ks)
            af[ks] = *(const bf16x8*)&h1s[p][(mt * 16 + ml) * 168 + ks * 32 + kg * 8];

        float sc[4] = {0.f, 0.f, 0.f, 0.f};
        #pragma unroll
        for (int j = 0; j < 5; ++j) {
            int nt = nt0 + j;
            f32x4 a2 = {0.f, 0.f, 0.f, 0.f};
            #pragma unroll
            for (int ks = 0; ks < 5; ++ks) {
                bf16x8 bf = *(const bf16x8*)&fW2[(long)(((nt * 5 + ks) << 6) | lane) << 3];
                a2 = __builtin_amdgcn_mfma_f32_16x16x32_bf16(af[ks], bf, a2, 0, 0, 0);
            }
            int col = nt * 16 + ml;
            float b2v = b2s[col], w3v = W3s[col];
            #pragma unroll
            for (int r = 0; r < 4; ++r)
                sc[r] += fmaxf(a2[r] + b2v, 0.f) * w3v;
        }
        #pragma unroll
        for (int r = 0; r < 4; ++r) {
            sc[r] += __shfl_xor(sc[r], 1);
            sc[r] += __shfl_xor(sc[r], 2);
            sc[r] += __shfl_xor(sc[r], 4);
            sc[r] += __shfl_xor(sc[r], 8);
        }
        if (ml == 0) {
            #pragma unroll
            for (int r = 0; r < 4; ++r)
                red[p][mt * 16 + kg * 4 + r][w & 1] = sc[r];
        }
        __syncthreads();
        if (tid < 32) {
            int S = T_LEN - n + 1;
            int off = (n - 1) * (T_LEN + 1) - (n - 1) * n / 2;
            int sr = s0 + tid;
            if (sr < S) out[off + sr] = red[p][tid][0] + red[p][tid][1] + bb;
        }
    }
}

// ---------------------------------------------------------------------------
extern "C" void kernel_launch(void* const* d_in, const int* in_sizes, int n_in,
                              void* d_out, int out_size, void* d_ws, size_t ws_size,
                              hipStream_t stream) {
    const float* embeds  = (const float*)d_in[0];
    const float* states  = (const float*)d_in[1];
    const float* attn_W1 = (const float*)d_in[2];
    const float* attn_b1 = (const float*)d_in[3];
    const float* attn_W2 = (const float*)d_in[4];
    const float* attn_b2 = (const float*)d_in[5];
    const float* attn_W3 = (const float*)d_in[6];
    const float* attn_b3 = (const float*)d_in[7];
    const float* sc_W1   = (const float*)d_in[8];
    const float* sc_b1   = (const float*)d_in[9];
    const float* sc_W2   = (const float*)d_in[10];
    const float* sc_b2   = (const float*)d_in[11];
    const float* sc_W3   = (const float*)d_in[12];
    const float* sc_b3   = (const float*)d_in[13];
    float* out = (float*)d_out;

    short* wsS = (short*)d_ws;
    short* Ubf = wsS;                         // [20000][160] bf16
    short* Vbf = wsS + 3200256;
    short* Pbf = wsS + 6400512;
    short* frag = wsS + 9600768;              // 302,080 shorts
    float* logits = (float*)(wsS + 9902848);  // 20,000 floats

    wprep<<<1180, 256, 0, stream>>>(sc_W1, attn_W1, attn_W2, sc_W2, frag);
    fusedAP<<<1250, 256, 0, stream>>>(states, embeds, frag, sc_b1, attn_b1,
                                      attn_b2, attn_W3, attn_b3,
                                      Ubf, Vbf, Pbf, logits);
    span_all<<<dim3(625, 2), 256, 0, stream>>>(Ubf, Vbf, Pbf, logits,
                                               frag + 276480, sc_b2, sc_W3, sc_b3,
                                               out);
}